// Round 1
// baseline (926.439 us; speedup 1.0000x reference)
//
#include <hip/hip_runtime.h>
#include <hip/hip_bf16.h>

// Problem constants (validated against in_sizes at launch)
#define NNODES 100000
#define NEDGES 1600000
#define IN_DIM 32
#define HID 64
#define H1 2
#define F1 (H1 * HID)   // 128
#define OUT_CH 64
#define NEG_SLOPE 0.2f
#define LN_EPS 1e-5f

__device__ __forceinline__ float leaky(float x) {
    return x > 0.f ? x : NEG_SLOPE * x;
}

// ---------------- CSR build ----------------

__global__ __launch_bounds__(256) void k_hist(const int* __restrict__ dst, int E,
                                              int* __restrict__ cnt) {
    int i = blockIdx.x * blockDim.x + threadIdx.x;
    if (i < E) atomicAdd(&cnt[dst[i]], 1);
}

// single-block exclusive scan over n counts -> rowptr
__global__ __launch_bounds__(1024) void k_scan(const int* __restrict__ cnt,
                                               int* __restrict__ rowptr, int n) {
    __shared__ int ssum[1024];
    int t = threadIdx.x;
    int chunk = (n + 1023) / 1024;
    int lo = t * chunk;
    int hi = lo + chunk; if (hi > n) hi = n;
    int s = 0;
    for (int i = lo; i < hi; i++) s += cnt[i];
    ssum[t] = s;
    __syncthreads();
    // Hillis-Steele inclusive scan over 1024 entries
    for (int off = 1; off < 1024; off <<= 1) {
        int v = (t >= off) ? ssum[t - off] : 0;
        __syncthreads();
        ssum[t] += v;
        __syncthreads();
    }
    int prefix = (t == 0) ? 0 : ssum[t - 1];
    for (int i = lo; i < hi; i++) { rowptr[i] = prefix; prefix += cnt[i]; }
}

__global__ __launch_bounds__(256) void k_scatter(const int* __restrict__ src,
                                                 const int* __restrict__ dst, int E,
                                                 const int* __restrict__ rowptr,
                                                 int* __restrict__ fill,
                                                 int* __restrict__ col) {
    int i = blockIdx.x * blockDim.x + threadIdx.x;
    if (i < E) {
        int d = dst[i];
        int pos = rowptr[d] + atomicAdd(&fill[d], 1);
        col[pos] = src[i];
    }
}

// ---------------- Layer 1: node transform (h1 = x@W1, att coefs) ----------------
// 2 nodes per 256-thread block; 128 threads per node (one thread per out channel).
// Waves: tid 0-63 = head0/node0, 64-127 = head1/node0, etc. -> wave reduce = per-head reduce.
__global__ __launch_bounds__(256) void k_node1(const float* __restrict__ x,
                                               const float* __restrict__ W1,
                                               const float* __restrict__ att_s,
                                               const float* __restrict__ att_d,
                                               float* __restrict__ h1,
                                               float* __restrict__ as1,
                                               float* __restrict__ ad1, int n) {
    int local = threadIdx.x >> 7;            // 0..1
    int node = blockIdx.x * 2 + local;
    int c = threadIdx.x & 127;               // out channel 0..127
    __shared__ float xs[2][IN_DIM];
    if (node < n && c < IN_DIM) xs[local][c] = x[(size_t)node * IN_DIM + c];
    __syncthreads();
    if (node >= n) return;
    float acc = 0.f;
#pragma unroll
    for (int k = 0; k < IN_DIM; k++) acc = fmaf(xs[local][k], W1[k * F1 + c], acc);
    h1[(size_t)node * F1 + c] = acc;
    // att arrays are [H1, HID] flattened = indexed directly by c
    float ps = acc * att_s[c];
    float pd = acc * att_d[c];
#pragma unroll
    for (int off = 32; off; off >>= 1) {
        ps += __shfl_down(ps, off, 64);
        pd += __shfl_down(pd, off, 64);
    }
    if ((c & 63) == 0) {
        int head = c >> 6;
        as1[node * 2 + head] = ps;
        ad1[node * 2 + head] = pd;
    }
}

// ---------------- Layer 1 aggregation + bias + LayerNorm + ReLU ----------------
// One wave per destination node; lane handles channels {lane, lane+64}.
// No max-subtraction in softmax: logits are O(+-5), fp32 exp is exact enough.
__global__ __launch_bounds__(256) void k_agg1(const float* __restrict__ h1,
                                              const float* __restrict__ as1,
                                              const float* __restrict__ ad1,
                                              const int* __restrict__ rowptr,
                                              const int* __restrict__ cnt,
                                              const int* __restrict__ col,
                                              const float* __restrict__ bias1,
                                              const float* __restrict__ gamma,
                                              const float* __restrict__ beta,
                                              float* __restrict__ hln, int n) {
    int node = blockIdx.x * 4 + (threadIdx.x >> 6);
    int lane = threadIdx.x & 63;
    if (node >= n) return;
    float adh0 = ad1[node * 2 + 0], adh1 = ad1[node * 2 + 1];
    // self-loop contribution
    float w0 = __expf(leaky(as1[node * 2 + 0] + adh0));
    float w1 = __expf(leaky(as1[node * 2 + 1] + adh1));
    const float* hrow = h1 + (size_t)node * F1;
    float acc0 = w0 * hrow[lane];
    float acc1 = w1 * hrow[64 + lane];
    float wsum0 = w0, wsum1 = w1;
    int start = rowptr[node], deg = cnt[node];
    for (int i = 0; i < deg; i++) {
        int s = col[start + i];                 // wave-uniform
        float ww0 = __expf(leaky(as1[s * 2 + 0] + adh0));
        float ww1 = __expf(leaky(as1[s * 2 + 1] + adh1));
        const float* hs = h1 + (size_t)s * F1;
        acc0 = fmaf(ww0, hs[lane], acc0);
        acc1 = fmaf(ww1, hs[64 + lane], acc1);
        wsum0 += ww0; wsum1 += ww1;
    }
    float o0 = acc0 / (wsum0 + 1e-16f) + bias1[lane];
    float o1 = acc1 / (wsum1 + 1e-16f) + bias1[64 + lane];
    // LayerNorm over the 128 features (2 per lane) + ReLU
    float sum = o0 + o1, sq = o0 * o0 + o1 * o1;
#pragma unroll
    for (int off = 32; off; off >>= 1) {
        sum += __shfl_xor(sum, off, 64);
        sq += __shfl_xor(sq, off, 64);
    }
    float mu = sum * (1.f / 128.f);
    float var = sq * (1.f / 128.f) - mu * mu;
    float r = rsqrtf(var + LN_EPS);
    float v0 = (o0 - mu) * r * gamma[lane] + beta[lane];
    float v1 = (o1 - mu) * r * gamma[64 + lane] + beta[64 + lane];
    hln[(size_t)node * F1 + lane] = fmaxf(v0, 0.f);
    hln[(size_t)node * F1 + 64 + lane] = fmaxf(v1, 0.f);
}

// ---------------- Layer 2: node transform (h2 = hln@W2, att coefs) ----------------
// 4 nodes per block, 64 threads (one wave) per node.
__global__ __launch_bounds__(256) void k_node2(const float* __restrict__ hln,
                                               const float* __restrict__ W2,
                                               const float* __restrict__ att_s2,
                                               const float* __restrict__ att_d2,
                                               float* __restrict__ h2,
                                               float* __restrict__ as2,
                                               float* __restrict__ ad2, int n) {
    int local = threadIdx.x >> 6;            // 0..3
    int node = blockIdx.x * 4 + local;
    int lane = threadIdx.x & 63;
    __shared__ float xs[4][F1];
    if (node < n) {
        xs[local][lane] = hln[(size_t)node * F1 + lane];
        xs[local][lane + 64] = hln[(size_t)node * F1 + 64 + lane];
    }
    __syncthreads();
    if (node >= n) return;
    float acc = 0.f;
#pragma unroll 8
    for (int k = 0; k < F1; k++) acc = fmaf(xs[local][k], W2[k * OUT_CH + lane], acc);
    h2[(size_t)node * OUT_CH + lane] = acc;
    float ps = acc * att_s2[lane];
    float pd = acc * att_d2[lane];
#pragma unroll
    for (int off = 32; off; off >>= 1) {
        ps += __shfl_down(ps, off, 64);
        pd += __shfl_down(pd, off, 64);
    }
    if (lane == 0) { as2[node] = ps; ad2[node] = pd; }
}

// ---------------- Layer 2 aggregation + bias -> output ----------------
__global__ __launch_bounds__(256) void k_agg2(const float* __restrict__ h2,
                                              const float* __restrict__ as2,
                                              const float* __restrict__ ad2,
                                              const int* __restrict__ rowptr,
                                              const int* __restrict__ cnt,
                                              const int* __restrict__ col,
                                              const float* __restrict__ bias2,
                                              float* __restrict__ out, int n) {
    int node = blockIdx.x * 4 + (threadIdx.x >> 6);
    int lane = threadIdx.x & 63;
    if (node >= n) return;
    float adv = ad2[node];
    float w = __expf(leaky(as2[node] + adv));       // self loop
    float acc = w * h2[(size_t)node * OUT_CH + lane];
    float wsum = w;
    int start = rowptr[node], deg = cnt[node];
    for (int i = 0; i < deg; i++) {
        int s = col[start + i];
        float ww = __expf(leaky(as2[s] + adv));
        acc = fmaf(ww, h2[(size_t)s * OUT_CH + lane], acc);
        wsum += ww;
    }
    out[(size_t)node * OUT_CH + lane] = acc / (wsum + 1e-16f) + bias2[lane];
}

extern "C" void kernel_launch(void* const* d_in, const int* in_sizes, int n_in,
                              void* d_out, int out_size, void* d_ws, size_t ws_size,
                              hipStream_t stream) {
    const float* x        = (const float*)d_in[0];
    const int*   eidx     = (const int*)d_in[1];
    const float* W1       = (const float*)d_in[2];
    const float* att_src1 = (const float*)d_in[3];
    const float* att_dst1 = (const float*)d_in[4];
    const float* bias1    = (const float*)d_in[5];
    const float* gamma    = (const float*)d_in[6];
    const float* beta     = (const float*)d_in[7];
    const float* W2       = (const float*)d_in[8];
    const float* att_src2 = (const float*)d_in[9];
    const float* att_dst2 = (const float*)d_in[10];
    const float* bias2    = (const float*)d_in[11];
    float* out = (float*)d_out;

    const int N = in_sizes[0] / IN_DIM;      // 100000
    const int E = in_sizes[1] / 2;           // 1600000
    const int* src = eidx;
    const int* dst = eidx + E;

    // Workspace carve-up (all sizes 16B-multiples). Peak ~112 MB.
    char* w = (char*)d_ws;
    float* h1  = (float*)w; w += (size_t)N * F1 * 4;     // 51.2 MB (reused as h2)
    float* hln = (float*)w; w += (size_t)N * F1 * 4;     // 51.2 MB
    float* as1 = (float*)w; w += (size_t)N * 2 * 4;
    float* ad1 = (float*)w; w += (size_t)N * 2 * 4;
    float* as2 = (float*)w; w += (size_t)N * 4;
    float* ad2 = (float*)w; w += (size_t)N * 4;
    int* cnt    = (int*)w; w += (size_t)N * 4;
    int* rowptr = (int*)w; w += (size_t)N * 4;
    int* fill   = (int*)w; w += (size_t)N * 4;
    int* col    = (int*)w; w += (size_t)E * 4;
    float* h2 = h1;   // h1 is dead after k_agg1; alias to cut peak ws

    // ---- CSR build by destination (shared by both layers) ----
    hipMemsetAsync(cnt, 0, (size_t)N * 4, stream);
    hipMemsetAsync(fill, 0, (size_t)N * 4, stream);
    k_hist<<<(E + 255) / 256, 256, 0, stream>>>(dst, E, cnt);
    k_scan<<<1, 1024, 0, stream>>>(cnt, rowptr, N);
    k_scatter<<<(E + 255) / 256, 256, 0, stream>>>(src, dst, E, rowptr, fill, col);

    // ---- Layer 1 ----
    k_node1<<<(N + 1) / 2, 256, 0, stream>>>(x, W1, att_src1, att_dst1, h1, as1, ad1, N);
    k_agg1<<<(N + 3) / 4, 256, 0, stream>>>(h1, as1, ad1, rowptr, cnt, col,
                                            bias1, gamma, beta, hln, N);
    // ---- Layer 2 ----
    k_node2<<<(N + 3) / 4, 256, 0, stream>>>(hln, W2, att_src2, att_dst2, h2, as2, ad2, N);
    k_agg2<<<(N + 3) / 4, 256, 0, stream>>>(h2, as2, ad2, rowptr, cnt, col,
                                            bias2, out, N);
}

// Round 2
// 748.489 us; speedup vs baseline: 1.2377x; 1.2377x over previous
//
#include <hip/hip_runtime.h>
#include <hip/hip_bf16.h>

#define IN_DIM 32
#define HID 64
#define H1 2
#define F1 (H1 * HID)   // 128
#define OUT_CH 64
#define NEG_SLOPE 0.2f
#define LN_EPS 1e-5f

__device__ __forceinline__ float leaky(float x) {
    return x > 0.f ? x : NEG_SLOPE * x;
}
__device__ __forceinline__ float bf2f(__hip_bfloat16 v) { return __bfloat162float(v); }

// ---------------- CSR build ----------------

__global__ __launch_bounds__(256) void k_hist(const int* __restrict__ dst, int E,
                                              int* __restrict__ cnt) {
    int i = blockIdx.x * blockDim.x + threadIdx.x;
    if (i < E) atomicAdd(&cnt[dst[i]], 1);
}

__global__ __launch_bounds__(1024) void k_scan(const int* __restrict__ cnt,
                                               int* __restrict__ rowptr, int n) {
    __shared__ int ssum[1024];
    int t = threadIdx.x;
    int chunk = (n + 1023) / 1024;
    int lo = t * chunk;
    int hi = lo + chunk; if (hi > n) hi = n;
    int s = 0;
    for (int i = lo; i < hi; i++) s += cnt[i];
    ssum[t] = s;
    __syncthreads();
    for (int off = 1; off < 1024; off <<= 1) {
        int v = (t >= off) ? ssum[t - off] : 0;
        __syncthreads();
        ssum[t] += v;
        __syncthreads();
    }
    int prefix = (t == 0) ? 0 : ssum[t - 1];
    for (int i = lo; i < hi; i++) { rowptr[i] = prefix; prefix += cnt[i]; }
}

__global__ __launch_bounds__(256) void k_scatter(const int* __restrict__ src,
                                                 const int* __restrict__ dst, int E,
                                                 const int* __restrict__ rowptr,
                                                 int* __restrict__ fill,
                                                 int* __restrict__ col) {
    int i = blockIdx.x * blockDim.x + threadIdx.x;
    if (i < E) {
        int d = dst[i];
        int pos = rowptr[d] + atomicAdd(&fill[d], 1);
        col[pos] = src[i];
    }
}

// ---------------- Layer 1: node transform -> bf16 h1, att coefs ----------------
// 4 nodes/block, 1 wave/node. Lane computes channels {2*lane, 2*lane+1} (same head).
__global__ __launch_bounds__(256) void k_node1(const float* __restrict__ x,
                                               const float* __restrict__ W1,
                                               const float* __restrict__ att_s,
                                               const float* __restrict__ att_d,
                                               __hip_bfloat162* __restrict__ h1b,
                                               float* __restrict__ as1,
                                               float* __restrict__ ad1, int n) {
    int local = threadIdx.x >> 6;
    int node = blockIdx.x * 4 + local;
    int lane = threadIdx.x & 63;
    __shared__ float xs[4][IN_DIM];
    if (node < n && lane < IN_DIM) xs[local][lane] = x[(size_t)node * IN_DIM + lane];
    __syncthreads();
    if (node >= n) return;
    const float2* W1v = (const float2*)W1;   // [32][64] float2
    float acc0 = 0.f, acc1 = 0.f;
#pragma unroll
    for (int k = 0; k < IN_DIM; k++) {
        float xv = xs[local][k];
        float2 w = W1v[k * 64 + lane];
        acc0 = fmaf(xv, w.x, acc0);
        acc1 = fmaf(xv, w.y, acc1);
    }
    __hip_bfloat162 hv;
    hv.x = __float2bfloat16(acc0);
    hv.y = __float2bfloat16(acc1);
    h1b[(size_t)node * 64 + lane] = hv;
    float2 asv = ((const float2*)att_s)[lane];
    float2 adv = ((const float2*)att_d)[lane];
    float ps = acc0 * asv.x + acc1 * asv.y;
    float pd = acc0 * adv.x + acc1 * adv.y;
#pragma unroll
    for (int off = 16; off; off >>= 1) {       // reduce within 32-lane half = one head
        ps += __shfl_down(ps, off, 32);
        pd += __shfl_down(pd, off, 32);
    }
    if ((lane & 31) == 0) {
        int head = lane >> 5;
        as1[node * 2 + head] = ps;
        ad1[node * 2 + head] = pd;
    }
}

// ---------------- Layer 1 aggregation + bias + LayerNorm + ReLU ----------------
// 1 wave/node; lane handles channels {2*lane, 2*lane+1} (one head per lane).
// col chunk loaded coalesced per wave, broadcast via shfl; edge loop unrolled x4.
__global__ __launch_bounds__(256) void k_agg1(const __hip_bfloat162* __restrict__ h1b,
                                              const float* __restrict__ as1,
                                              const float* __restrict__ ad1,
                                              const int* __restrict__ rowptr,
                                              const int* __restrict__ cnt,
                                              const int* __restrict__ col,
                                              const float* __restrict__ bias1,
                                              const float* __restrict__ gamma,
                                              const float* __restrict__ beta,
                                              float2* __restrict__ hln, int n) {
    int node = blockIdx.x * 4 + (threadIdx.x >> 6);
    int lane = threadIdx.x & 63;
    if (node >= n) return;
    int head = lane >> 5;
    float ad = ad1[node * 2 + head];
    // self-loop seed
    float w = __expf(leaky(as1[node * 2 + head] + ad));
    __hip_bfloat162 hv = h1b[(size_t)node * 64 + lane];
    float acc0 = w * bf2f(hv.x), acc1 = w * bf2f(hv.y), wsum = w;
    int start = rowptr[node], deg = cnt[node];
    for (int base = 0; base < deg; base += 64) {
        int m = min(64, deg - base);
        int colv = (lane < m) ? col[start + base + lane] : 0;
        int j = 0;
        for (; j + 4 <= m; j += 4) {
            int s0 = __shfl(colv, j + 0);
            int s1 = __shfl(colv, j + 1);
            int s2 = __shfl(colv, j + 2);
            int s3 = __shfl(colv, j + 3);
            float e0 = as1[s0 * 2 + head];
            float e1 = as1[s1 * 2 + head];
            float e2 = as1[s2 * 2 + head];
            float e3 = as1[s3 * 2 + head];
            __hip_bfloat162 g0 = h1b[(size_t)s0 * 64 + lane];
            __hip_bfloat162 g1 = h1b[(size_t)s1 * 64 + lane];
            __hip_bfloat162 g2 = h1b[(size_t)s2 * 64 + lane];
            __hip_bfloat162 g3 = h1b[(size_t)s3 * 64 + lane];
            float w0 = __expf(leaky(e0 + ad));
            float w1 = __expf(leaky(e1 + ad));
            float w2 = __expf(leaky(e2 + ad));
            float w3 = __expf(leaky(e3 + ad));
            acc0 = fmaf(w0, bf2f(g0.x), acc0); acc1 = fmaf(w0, bf2f(g0.y), acc1);
            acc0 = fmaf(w1, bf2f(g1.x), acc0); acc1 = fmaf(w1, bf2f(g1.y), acc1);
            acc0 = fmaf(w2, bf2f(g2.x), acc0); acc1 = fmaf(w2, bf2f(g2.y), acc1);
            acc0 = fmaf(w3, bf2f(g3.x), acc0); acc1 = fmaf(w3, bf2f(g3.y), acc1);
            wsum += w0 + w1 + w2 + w3;
        }
        for (; j < m; j++) {
            int s = __shfl(colv, j);
            float ww = __expf(leaky(as1[s * 2 + head] + ad));
            __hip_bfloat162 g = h1b[(size_t)s * 64 + lane];
            acc0 = fmaf(ww, bf2f(g.x), acc0);
            acc1 = fmaf(ww, bf2f(g.y), acc1);
            wsum += ww;
        }
    }
    float2 bv = ((const float2*)bias1)[lane];
    float o0 = acc0 / (wsum + 1e-16f) + bv.x;
    float o1 = acc1 / (wsum + 1e-16f) + bv.y;
    float sum = o0 + o1, sq = o0 * o0 + o1 * o1;
#pragma unroll
    for (int off = 32; off; off >>= 1) {
        sum += __shfl_xor(sum, off, 64);
        sq += __shfl_xor(sq, off, 64);
    }
    float mu = sum * (1.f / 128.f);
    float var = sq * (1.f / 128.f) - mu * mu;
    float r = rsqrtf(var + LN_EPS);
    float2 gv = ((const float2*)gamma)[lane];
    float2 btv = ((const float2*)beta)[lane];
    float v0 = (o0 - mu) * r * gv.x + btv.x;
    float v1 = (o1 - mu) * r * gv.y + btv.y;
    float2 ov; ov.x = fmaxf(v0, 0.f); ov.y = fmaxf(v1, 0.f);
    hln[(size_t)node * 64 + lane] = ov;
}

// ---------------- Layer 2: node transform -> bf16 h2, att coefs ----------------
__global__ __launch_bounds__(256) void k_node2(const float2* __restrict__ hln,
                                               const float* __restrict__ W2,
                                               const float* __restrict__ att_s2,
                                               const float* __restrict__ att_d2,
                                               __hip_bfloat16* __restrict__ h2b,
                                               float* __restrict__ as2,
                                               float* __restrict__ ad2, int n) {
    int local = threadIdx.x >> 6;
    int node = blockIdx.x * 4 + local;
    int lane = threadIdx.x & 63;
    __shared__ float xs[4][F1];
    if (node < n) {
        ((float2*)xs[local])[lane] = hln[(size_t)node * 64 + lane];
    }
    __syncthreads();
    if (node >= n) return;
    float acc = 0.f;
#pragma unroll 8
    for (int k = 0; k < F1; k++) acc = fmaf(xs[local][k], W2[k * OUT_CH + lane], acc);
    h2b[(size_t)node * OUT_CH + lane] = __float2bfloat16(acc);
    float ps = acc * att_s2[lane];
    float pd = acc * att_d2[lane];
#pragma unroll
    for (int off = 32; off; off >>= 1) {
        ps += __shfl_down(ps, off, 64);
        pd += __shfl_down(pd, off, 64);
    }
    if (lane == 0) { as2[node] = ps; ad2[node] = pd; }
}

// ---------------- Layer 2 aggregation + bias -> output ----------------
__global__ __launch_bounds__(256) void k_agg2(const __hip_bfloat16* __restrict__ h2b,
                                              const float* __restrict__ as2,
                                              const float* __restrict__ ad2,
                                              const int* __restrict__ rowptr,
                                              const int* __restrict__ cnt,
                                              const int* __restrict__ col,
                                              const float* __restrict__ bias2,
                                              float* __restrict__ out, int n) {
    int node = blockIdx.x * 4 + (threadIdx.x >> 6);
    int lane = threadIdx.x & 63;
    if (node >= n) return;
    float adv = ad2[node];
    float w = __expf(leaky(as2[node] + adv));
    float acc = w * bf2f(h2b[(size_t)node * OUT_CH + lane]);
    float wsum = w;
    int start = rowptr[node], deg = cnt[node];
    for (int base = 0; base < deg; base += 64) {
        int m = min(64, deg - base);
        int colv = (lane < m) ? col[start + base + lane] : 0;
        int j = 0;
        for (; j + 4 <= m; j += 4) {
            int s0 = __shfl(colv, j + 0);
            int s1 = __shfl(colv, j + 1);
            int s2 = __shfl(colv, j + 2);
            int s3 = __shfl(colv, j + 3);
            float e0 = as2[s0], e1 = as2[s1], e2 = as2[s2], e3 = as2[s3];
            __hip_bfloat16 g0 = h2b[(size_t)s0 * OUT_CH + lane];
            __hip_bfloat16 g1 = h2b[(size_t)s1 * OUT_CH + lane];
            __hip_bfloat16 g2 = h2b[(size_t)s2 * OUT_CH + lane];
            __hip_bfloat16 g3 = h2b[(size_t)s3 * OUT_CH + lane];
            float w0 = __expf(leaky(e0 + adv));
            float w1 = __expf(leaky(e1 + adv));
            float w2 = __expf(leaky(e2 + adv));
            float w3 = __expf(leaky(e3 + adv));
            acc = fmaf(w0, bf2f(g0), acc);
            acc = fmaf(w1, bf2f(g1), acc);
            acc = fmaf(w2, bf2f(g2), acc);
            acc = fmaf(w3, bf2f(g3), acc);
            wsum += w0 + w1 + w2 + w3;
        }
        for (; j < m; j++) {
            int s = __shfl(colv, j);
            float ww = __expf(leaky(as2[s] + adv));
            acc = fmaf(ww, bf2f(h2b[(size_t)s * OUT_CH + lane]), acc);
            wsum += ww;
        }
    }
    out[(size_t)node * OUT_CH + lane] = acc / (wsum + 1e-16f) + bias2[lane];
}

extern "C" void kernel_launch(void* const* d_in, const int* in_sizes, int n_in,
                              void* d_out, int out_size, void* d_ws, size_t ws_size,
                              hipStream_t stream) {
    const float* x        = (const float*)d_in[0];
    const int*   eidx     = (const int*)d_in[1];
    const float* W1       = (const float*)d_in[2];
    const float* att_src1 = (const float*)d_in[3];
    const float* att_dst1 = (const float*)d_in[4];
    const float* bias1    = (const float*)d_in[5];
    const float* gamma    = (const float*)d_in[6];
    const float* beta     = (const float*)d_in[7];
    const float* W2       = (const float*)d_in[8];
    const float* att_src2 = (const float*)d_in[9];
    const float* att_dst2 = (const float*)d_in[10];
    const float* bias2    = (const float*)d_in[11];
    float* out = (float*)d_out;

    const int N = in_sizes[0] / IN_DIM;      // 100000
    const int E = in_sizes[1] / 2;           // 1600000
    const int* src = eidx;
    const int* dst = eidx + E;

    char* w = (char*)d_ws;
    __hip_bfloat162* h1b = (__hip_bfloat162*)w; w += (size_t)N * 64 * 4;   // 25.6 MB
    float2* hln = (float2*)w;                   w += (size_t)N * 64 * 8;   // 51.2 MB
    __hip_bfloat16* h2b = (__hip_bfloat16*)w;   w += (size_t)N * 64 * 2;   // 12.8 MB
    float* as1 = (float*)w; w += (size_t)N * 2 * 4;
    float* ad1 = (float*)w; w += (size_t)N * 2 * 4;
    float* as2 = (float*)w; w += (size_t)N * 4;
    float* ad2 = (float*)w; w += (size_t)N * 4;
    int* cnt    = (int*)w; w += (size_t)N * 4;
    int* rowptr = (int*)w; w += (size_t)N * 4;
    int* fill   = (int*)w; w += (size_t)N * 4;
    int* col    = (int*)w; w += (size_t)E * 4;

    // ---- CSR build by destination (shared by both layers) ----
    hipMemsetAsync(cnt, 0, (size_t)N * 4, stream);
    hipMemsetAsync(fill, 0, (size_t)N * 4, stream);
    k_hist<<<(E + 255) / 256, 256, 0, stream>>>(dst, E, cnt);
    k_scan<<<1, 1024, 0, stream>>>(cnt, rowptr, N);
    k_scatter<<<(E + 255) / 256, 256, 0, stream>>>(src, dst, E, rowptr, fill, col);

    // ---- Layer 1 ----
    k_node1<<<(N + 3) / 4, 256, 0, stream>>>(x, W1, att_src1, att_dst1, h1b, as1, ad1, N);
    k_agg1<<<(N + 3) / 4, 256, 0, stream>>>(h1b, as1, ad1, rowptr, cnt, col,
                                            bias1, gamma, beta, hln, N);
    // ---- Layer 2 ----
    k_node2<<<(N + 3) / 4, 256, 0, stream>>>(hln, W2, att_src2, att_dst2, h2b, as2, ad2, N);
    k_agg2<<<(N + 3) / 4, 256, 0, stream>>>(h2b, as2, ad2, rowptr, cnt, col,
                                            bias2, out, N);
}

// Round 3
// 614.461 us; speedup vs baseline: 1.5077x; 1.2181x over previous
//
#include <hip/hip_runtime.h>
#include <hip/hip_bf16.h>

#define IN_DIM 32
#define HID 64
#define H1 2
#define F1 (H1 * HID)   // 128
#define OUT_CH 64
#define NEG_SLOPE 0.2f
#define LN_EPS 1e-5f

__device__ __forceinline__ float leaky(float x) {
    return x > 0.f ? x : NEG_SLOPE * x;
}
__device__ __forceinline__ float bf2f(__hip_bfloat16 v) { return __bfloat162float(v); }

// ---------------- CSR build ----------------

__global__ __launch_bounds__(256) void k_hist(const int* __restrict__ dst, int E,
                                              int* __restrict__ cnt) {
    int i = blockIdx.x * blockDim.x + threadIdx.x;
    if (i < E) atomicAdd(&cnt[dst[i]], 1);
}

// ---- multi-block exclusive scan: 1024 elements per 256-thread block (int4) ----
__global__ __launch_bounds__(256) void k_scan1(const int* __restrict__ cnt, int n,
                                               int* __restrict__ bsum) {
    int t = threadIdx.x;
    int idx = blockIdx.x * 1024 + t * 4;
    int4 v = {0, 0, 0, 0};
    if (idx + 3 < n) v = *(const int4*)(cnt + idx);
    else {
        if (idx + 0 < n) v.x = cnt[idx + 0];
        if (idx + 1 < n) v.y = cnt[idx + 1];
        if (idx + 2 < n) v.z = cnt[idx + 2];
    }
    __shared__ int red[256];
    red[t] = v.x + v.y + v.z + v.w;
    __syncthreads();
    for (int off = 128; off; off >>= 1) {
        if (t < off) red[t] += red[t + off];
        __syncthreads();
    }
    if (t == 0) bsum[blockIdx.x] = red[0];
}

__global__ __launch_bounds__(1024) void k_scan2(int* __restrict__ bsum, int nb) {
    __shared__ int s[1024];
    int t = threadIdx.x;
    int v = (t < nb) ? bsum[t] : 0;
    s[t] = v;
    __syncthreads();
    for (int off = 1; off < 1024; off <<= 1) {
        int u = (t >= off) ? s[t - off] : 0;
        __syncthreads();
        s[t] += u;
        __syncthreads();
    }
    if (t < nb) bsum[t] = s[t] - v;   // exclusive
}

__global__ __launch_bounds__(256) void k_scan3(const int* __restrict__ cnt, int n,
                                               const int* __restrict__ bsum,
                                               int* __restrict__ rowptr,
                                               int* __restrict__ fill) {
    int t = threadIdx.x;
    int idx = blockIdx.x * 1024 + t * 4;
    int4 v = {0, 0, 0, 0};
    if (idx + 3 < n) v = *(const int4*)(cnt + idx);
    else {
        if (idx + 0 < n) v.x = cnt[idx + 0];
        if (idx + 1 < n) v.y = cnt[idx + 1];
        if (idx + 2 < n) v.z = cnt[idx + 2];
    }
    int s = v.x + v.y + v.z + v.w;
    __shared__ int sh[256];
    sh[t] = s;
    __syncthreads();
    for (int off = 1; off < 256; off <<= 1) {
        int u = (t >= off) ? sh[t - off] : 0;
        __syncthreads();
        sh[t] += u;
        __syncthreads();
    }
    int r0 = sh[t] - s + bsum[blockIdx.x];
    int r1 = r0 + v.x, r2 = r1 + v.y, r3 = r2 + v.z;
    if (idx + 3 < n) {
        *(int4*)(rowptr + idx) = make_int4(r0, r1, r2, r3);
        *(int4*)(fill + idx)   = make_int4(r0, r1, r2, r3);
    } else {
        if (idx + 0 < n) { rowptr[idx + 0] = r0; fill[idx + 0] = r0; }
        if (idx + 1 < n) { rowptr[idx + 1] = r1; fill[idx + 1] = r1; }
        if (idx + 2 < n) { rowptr[idx + 2] = r2; fill[idx + 2] = r2; }
    }
}

// fill[] pre-seeded with rowptr values; atomically bump to place each edge
__global__ __launch_bounds__(256) void k_scatter(const int* __restrict__ src,
                                                 const int* __restrict__ dst, int E,
                                                 int* __restrict__ fill,
                                                 int* __restrict__ col) {
    int i = blockIdx.x * blockDim.x + threadIdx.x;
    if (i < E) {
        int pos = atomicAdd(&fill[dst[i]], 1);
        col[pos] = src[i];
    }
}

// ---------------- Layer 1: node transform -> bf16 h1, att coefs ----------------
// 4 nodes/block, 1 wave/node. Lane computes channels {2*lane, 2*lane+1} (same head).
__global__ __launch_bounds__(256) void k_node1(const float* __restrict__ x,
                                               const float* __restrict__ W1,
                                               const float* __restrict__ att_s,
                                               const float* __restrict__ att_d,
                                               __hip_bfloat162* __restrict__ h1b,
                                               float* __restrict__ as1,
                                               float* __restrict__ ad1, int n) {
    int local = threadIdx.x >> 6;
    int node = blockIdx.x * 4 + local;
    int lane = threadIdx.x & 63;
    __shared__ float xs[4][IN_DIM];
    if (node < n && lane < IN_DIM) xs[local][lane] = x[(size_t)node * IN_DIM + lane];
    __syncthreads();
    if (node >= n) return;
    const float2* W1v = (const float2*)W1;   // [32][64] float2
    float acc0 = 0.f, acc1 = 0.f;
#pragma unroll
    for (int k = 0; k < IN_DIM; k++) {
        float xv = xs[local][k];
        float2 w = W1v[k * 64 + lane];
        acc0 = fmaf(xv, w.x, acc0);
        acc1 = fmaf(xv, w.y, acc1);
    }
    __hip_bfloat162 hv;
    hv.x = __float2bfloat16(acc0);
    hv.y = __float2bfloat16(acc1);
    h1b[(size_t)node * 64 + lane] = hv;
    float2 asv = ((const float2*)att_s)[lane];
    float2 adv = ((const float2*)att_d)[lane];
    float ps = acc0 * asv.x + acc1 * asv.y;
    float pd = acc0 * adv.x + acc1 * adv.y;
#pragma unroll
    for (int off = 16; off; off >>= 1) {       // reduce within 32-lane half = one head
        ps += __shfl_down(ps, off, 32);
        pd += __shfl_down(pd, off, 32);
    }
    if ((lane & 31) == 0) {
        int head = lane >> 5;
        as1[node * 2 + head] = ps;
        ad1[node * 2 + head] = pd;
    }
}

// ---------------- Layer 1 aggregation + bias + LayerNorm + ReLU ----------------
__global__ __launch_bounds__(256) void k_agg1(const __hip_bfloat162* __restrict__ h1b,
                                              const float* __restrict__ as1,
                                              const float* __restrict__ ad1,
                                              const int* __restrict__ rowptr,
                                              const int* __restrict__ cnt,
                                              const int* __restrict__ col,
                                              const float* __restrict__ bias1,
                                              const float* __restrict__ gamma,
                                              const float* __restrict__ beta,
                                              float2* __restrict__ hln, int n) {
    int node = blockIdx.x * 4 + (threadIdx.x >> 6);
    int lane = threadIdx.x & 63;
    if (node >= n) return;
    int head = lane >> 5;
    float ad = ad1[node * 2 + head];
    float w = __expf(leaky(as1[node * 2 + head] + ad));
    __hip_bfloat162 hv = h1b[(size_t)node * 64 + lane];
    float acc0 = w * bf2f(hv.x), acc1 = w * bf2f(hv.y), wsum = w;
    int start = rowptr[node], deg = cnt[node];
    for (int base = 0; base < deg; base += 64) {
        int m = min(64, deg - base);
        int colv = (lane < m) ? col[start + base + lane] : 0;
        int j = 0;
        for (; j + 4 <= m; j += 4) {
            int s0 = __shfl(colv, j + 0);
            int s1 = __shfl(colv, j + 1);
            int s2 = __shfl(colv, j + 2);
            int s3 = __shfl(colv, j + 3);
            float e0 = as1[s0 * 2 + head];
            float e1 = as1[s1 * 2 + head];
            float e2 = as1[s2 * 2 + head];
            float e3 = as1[s3 * 2 + head];
            __hip_bfloat162 g0 = h1b[(size_t)s0 * 64 + lane];
            __hip_bfloat162 g1 = h1b[(size_t)s1 * 64 + lane];
            __hip_bfloat162 g2 = h1b[(size_t)s2 * 64 + lane];
            __hip_bfloat162 g3 = h1b[(size_t)s3 * 64 + lane];
            float w0 = __expf(leaky(e0 + ad));
            float w1 = __expf(leaky(e1 + ad));
            float w2 = __expf(leaky(e2 + ad));
            float w3 = __expf(leaky(e3 + ad));
            acc0 = fmaf(w0, bf2f(g0.x), acc0); acc1 = fmaf(w0, bf2f(g0.y), acc1);
            acc0 = fmaf(w1, bf2f(g1.x), acc0); acc1 = fmaf(w1, bf2f(g1.y), acc1);
            acc0 = fmaf(w2, bf2f(g2.x), acc0); acc1 = fmaf(w2, bf2f(g2.y), acc1);
            acc0 = fmaf(w3, bf2f(g3.x), acc0); acc1 = fmaf(w3, bf2f(g3.y), acc1);
            wsum += w0 + w1 + w2 + w3;
        }
        for (; j < m; j++) {
            int s = __shfl(colv, j);
            float ww = __expf(leaky(as1[s * 2 + head] + ad));
            __hip_bfloat162 g = h1b[(size_t)s * 64 + lane];
            acc0 = fmaf(ww, bf2f(g.x), acc0);
            acc1 = fmaf(ww, bf2f(g.y), acc1);
            wsum += ww;
        }
    }
    float2 bv = ((const float2*)bias1)[lane];
    float o0 = acc0 / (wsum + 1e-16f) + bv.x;
    float o1 = acc1 / (wsum + 1e-16f) + bv.y;
    float sum = o0 + o1, sq = o0 * o0 + o1 * o1;
#pragma unroll
    for (int off = 32; off; off >>= 1) {
        sum += __shfl_xor(sum, off, 64);
        sq += __shfl_xor(sq, off, 64);
    }
    float mu = sum * (1.f / 128.f);
    float var = sq * (1.f / 128.f) - mu * mu;
    float r = rsqrtf(var + LN_EPS);
    float2 gv = ((const float2*)gamma)[lane];
    float2 btv = ((const float2*)beta)[lane];
    float v0 = (o0 - mu) * r * gv.x + btv.x;
    float v1 = (o1 - mu) * r * gv.y + btv.y;
    float2 ov; ov.x = fmaxf(v0, 0.f); ov.y = fmaxf(v1, 0.f);
    hln[(size_t)node * 64 + lane] = ov;
}

// ---------------- Layer 2: node transform -> bf16 h2, att coefs ----------------
__global__ __launch_bounds__(256) void k_node2(const float2* __restrict__ hln,
                                               const float* __restrict__ W2,
                                               const float* __restrict__ att_s2,
                                               const float* __restrict__ att_d2,
                                               __hip_bfloat16* __restrict__ h2b,
                                               float* __restrict__ as2,
                                               float* __restrict__ ad2, int n) {
    int local = threadIdx.x >> 6;
    int node = blockIdx.x * 4 + local;
    int lane = threadIdx.x & 63;
    __shared__ float xs[4][F1];
    if (node < n) {
        ((float2*)xs[local])[lane] = hln[(size_t)node * 64 + lane];
    }
    __syncthreads();
    if (node >= n) return;
    float acc = 0.f;
#pragma unroll 8
    for (int k = 0; k < F1; k++) acc = fmaf(xs[local][k], W2[k * OUT_CH + lane], acc);
    h2b[(size_t)node * OUT_CH + lane] = __float2bfloat16(acc);
    float ps = acc * att_s2[lane];
    float pd = acc * att_d2[lane];
#pragma unroll
    for (int off = 32; off; off >>= 1) {
        ps += __shfl_down(ps, off, 64);
        pd += __shfl_down(pd, off, 64);
    }
    if (lane == 0) { as2[node] = ps; ad2[node] = pd; }
}

// ---------------- Layer 2 aggregation + bias -> output ----------------
__global__ __launch_bounds__(256) void k_agg2(const __hip_bfloat16* __restrict__ h2b,
                                              const float* __restrict__ as2,
                                              const float* __restrict__ ad2,
                                              const int* __restrict__ rowptr,
                                              const int* __restrict__ cnt,
                                              const int* __restrict__ col,
                                              const float* __restrict__ bias2,
                                              float* __restrict__ out, int n) {
    int node = blockIdx.x * 4 + (threadIdx.x >> 6);
    int lane = threadIdx.x & 63;
    if (node >= n) return;
    float adv = ad2[node];
    float w = __expf(leaky(as2[node] + adv));
    float acc = w * bf2f(h2b[(size_t)node * OUT_CH + lane]);
    float wsum = w;
    int start = rowptr[node], deg = cnt[node];
    for (int base = 0; base < deg; base += 64) {
        int m = min(64, deg - base);
        int colv = (lane < m) ? col[start + base + lane] : 0;
        int j = 0;
        for (; j + 4 <= m; j += 4) {
            int s0 = __shfl(colv, j + 0);
            int s1 = __shfl(colv, j + 1);
            int s2 = __shfl(colv, j + 2);
            int s3 = __shfl(colv, j + 3);
            float e0 = as2[s0], e1 = as2[s1], e2 = as2[s2], e3 = as2[s3];
            __hip_bfloat16 g0 = h2b[(size_t)s0 * OUT_CH + lane];
            __hip_bfloat16 g1 = h2b[(size_t)s1 * OUT_CH + lane];
            __hip_bfloat16 g2 = h2b[(size_t)s2 * OUT_CH + lane];
            __hip_bfloat16 g3 = h2b[(size_t)s3 * OUT_CH + lane];
            float w0 = __expf(leaky(e0 + adv));
            float w1 = __expf(leaky(e1 + adv));
            float w2 = __expf(leaky(e2 + adv));
            float w3 = __expf(leaky(e3 + adv));
            acc = fmaf(w0, bf2f(g0), acc);
            acc = fmaf(w1, bf2f(g1), acc);
            acc = fmaf(w2, bf2f(g2), acc);
            acc = fmaf(w3, bf2f(g3), acc);
            wsum += w0 + w1 + w2 + w3;
        }
        for (; j < m; j++) {
            int s = __shfl(colv, j);
            float ww = __expf(leaky(as2[s] + adv));
            acc = fmaf(ww, bf2f(h2b[(size_t)s * OUT_CH + lane]), acc);
            wsum += ww;
        }
    }
    out[(size_t)node * OUT_CH + lane] = acc / (wsum + 1e-16f) + bias2[lane];
}

extern "C" void kernel_launch(void* const* d_in, const int* in_sizes, int n_in,
                              void* d_out, int out_size, void* d_ws, size_t ws_size,
                              hipStream_t stream) {
    const float* x        = (const float*)d_in[0];
    const int*   eidx     = (const int*)d_in[1];
    const float* W1       = (const float*)d_in[2];
    const float* att_src1 = (const float*)d_in[3];
    const float* att_dst1 = (const float*)d_in[4];
    const float* bias1    = (const float*)d_in[5];
    const float* gamma    = (const float*)d_in[6];
    const float* beta     = (const float*)d_in[7];
    const float* W2       = (const float*)d_in[8];
    const float* att_src2 = (const float*)d_in[9];
    const float* att_dst2 = (const float*)d_in[10];
    const float* bias2    = (const float*)d_in[11];
    float* out = (float*)d_out;

    const int N = in_sizes[0] / IN_DIM;      // 100000
    const int E = in_sizes[1] / 2;           // 1600000
    const int* src = eidx;
    const int* dst = eidx + E;

    char* w = (char*)d_ws;
    __hip_bfloat162* h1b = (__hip_bfloat162*)w; w += (size_t)N * 64 * 4;   // 25.6 MB
    float2* hln = (float2*)w;                   w += (size_t)N * 64 * 8;   // 51.2 MB
    __hip_bfloat16* h2b = (__hip_bfloat16*)w;   w += (size_t)N * 64 * 2;   // 12.8 MB
    float* as1 = (float*)w; w += (size_t)N * 2 * 4;
    float* ad1 = (float*)w; w += (size_t)N * 2 * 4;
    float* as2 = (float*)w; w += (size_t)N * 4;
    float* ad2 = (float*)w; w += (size_t)N * 4;
    int* cnt    = (int*)w; w += (size_t)N * 4;
    int* rowptr = (int*)w; w += (size_t)N * 4;
    int* fill   = (int*)w; w += (size_t)N * 4;
    int* bsum   = (int*)w; w += 4096;
    int* col    = (int*)w; w += (size_t)E * 4;

    const int nscan = (N + 1023) / 1024;     // 98 blocks

    // ---- CSR build by destination (shared by both layers) ----
    hipMemsetAsync(cnt, 0, (size_t)N * 4, stream);
    k_hist<<<(E + 255) / 256, 256, 0, stream>>>(dst, E, cnt);
    k_scan1<<<nscan, 256, 0, stream>>>(cnt, N, bsum);
    k_scan2<<<1, 1024, 0, stream>>>(bsum, nscan);
    k_scan3<<<nscan, 256, 0, stream>>>(cnt, N, bsum, rowptr, fill);
    k_scatter<<<(E + 255) / 256, 256, 0, stream>>>(src, dst, E, fill, col);

    // ---- Layer 1 ----
    k_node1<<<(N + 3) / 4, 256, 0, stream>>>(x, W1, att_src1, att_dst1, h1b, as1, ad1, N);
    k_agg1<<<(N + 3) / 4, 256, 0, stream>>>(h1b, as1, ad1, rowptr, cnt, col,
                                            bias1, gamma, beta, hln, N);
    // ---- Layer 2 ----
    k_node2<<<(N + 3) / 4, 256, 0, stream>>>(hln, W2, att_src2, att_dst2, h2b, as2, ad2, N);
    k_agg2<<<(N + 3) / 4, 256, 0, stream>>>(h2b, as2, ad2, rowptr, cnt, col,
                                            bias2, out, N);
}

// Round 4
// 487.204 us; speedup vs baseline: 1.9015x; 1.2612x over previous
//
#include <hip/hip_runtime.h>
#include <hip/hip_bf16.h>

#define IN_DIM 32
#define HID 64
#define H1 2
#define F1 (H1 * HID)   // 128
#define OUT_CH 64
#define NEG_SLOPE 0.2f
#define LN_EPS 1e-5f

#define BSHIFT 9                     // 512 nodes per bucket
#define BMASK ((1 << BSHIFT) - 1)
#define CHUNK 4096                   // edges per block in bucketing passes

__device__ __forceinline__ float leaky(float x) {
    return x > 0.f ? x : NEG_SLOPE * x;
}
__device__ __forceinline__ float bf2f(__hip_bfloat16 v) { return __bfloat162float(v); }

// ---------------- bucketed CSR build ----------------
// Level 1: bucket edges by dst>>9 (196 buckets); Level 2: per-bucket CSR in LDS.

__global__ __launch_bounds__(256) void k_bhist(const int* __restrict__ dst, int E, int nb,
                                               int* __restrict__ bcnt) {
    __shared__ int h[512];
    int t = threadIdx.x;
    for (int i = t; i < nb; i += 256) h[i] = 0;
    __syncthreads();
    int base = blockIdx.x * CHUNK;
#pragma unroll
    for (int j = 0; j < 16; j++) {
        int e = base + j * 256 + t;
        if (e < E) atomicAdd(&h[dst[e] >> BSHIFT], 1);
    }
    __syncthreads();
    for (int i = t; i < nb; i += 256)
        if (h[i]) atomicAdd(&bcnt[i], h[i]);
}

__global__ __launch_bounds__(512) void k_bscan(const int* __restrict__ bcnt, int nb, int E,
                                               int* __restrict__ boff,
                                               int* __restrict__ bfill) {
    __shared__ int s[512];
    int t = threadIdx.x;
    int v = (t < nb) ? bcnt[t] : 0;
    s[t] = v;
    __syncthreads();
    for (int off = 1; off < 512; off <<= 1) {
        int u = (t >= off) ? s[t - off] : 0;
        __syncthreads();
        s[t] += u;
        __syncthreads();
    }
    if (t < nb) { int ex = s[t] - v; boff[t] = ex; bfill[t] = ex; }
    if (t == 0) boff[nb] = E;
}

// rank edges per (block,bucket) in LDS, claim global run, write packed edges
__global__ __launch_bounds__(256) void k_bucket(const int* __restrict__ src,
                                                const int* __restrict__ dst, int E, int nb,
                                                int* __restrict__ bfill,
                                                unsigned int* __restrict__ bedge) {
    __shared__ int h[512];
    __shared__ int gb[512];
    int t = threadIdx.x;
    for (int i = t; i < nb; i += 256) h[i] = 0;
    __syncthreads();
    int base = blockIdx.x * CHUNK;
    unsigned int pk[16];
    int rk[16], bk[16];
#pragma unroll
    for (int j = 0; j < 16; j++) {
        int e = base + j * 256 + t;
        if (e < E) {
            int d = dst[e];
            int b = d >> BSHIFT;
            bk[j] = b;
            pk[j] = ((unsigned)src[e] << BSHIFT) | (unsigned)(d & BMASK);
            rk[j] = atomicAdd(&h[b], 1);
        } else bk[j] = -1;
    }
    __syncthreads();
    for (int i = t; i < nb; i += 256)
        gb[i] = h[i] ? atomicAdd(&bfill[i], h[i]) : 0;
    __syncthreads();
#pragma unroll
    for (int j = 0; j < 16; j++)
        if (bk[j] >= 0) bedge[gb[bk[j]] + rk[j]] = pk[j];
}

// one block per bucket: per-node counts + scan in LDS -> cnt/rowptr/col
__global__ __launch_bounds__(256) void k_csr(const unsigned int* __restrict__ bedge,
                                             const int* __restrict__ boff, int n,
                                             int* __restrict__ cnt,
                                             int* __restrict__ rowptr,
                                             int* __restrict__ col) {
    int b = blockIdx.x;
    int t = threadIdx.x;
    __shared__ int lcnt[512];
    __shared__ int lscan[256];
    int nbase = b << BSHIFT;
    lcnt[2 * t] = 0; lcnt[2 * t + 1] = 0;
    __syncthreads();
    int estart = boff[b], eend = boff[b + 1];
    for (int e = estart + t; e < eend; e += 256)
        atomicAdd(&lcnt[bedge[e] & BMASK], 1);
    __syncthreads();
    int c0 = lcnt[2 * t], c1 = lcnt[2 * t + 1];
    int s = c0 + c1;
    lscan[t] = s;
    __syncthreads();
    for (int off = 1; off < 256; off <<= 1) {
        int u = (t >= off) ? lscan[t - off] : 0;
        __syncthreads();
        lscan[t] += u;
        __syncthreads();
    }
    int ex = lscan[t] - s;                 // exclusive prefix over node pairs
    int node0 = nbase + 2 * t, node1 = node0 + 1;
    if (node0 < n) { cnt[node0] = c0; rowptr[node0] = estart + ex; }
    if (node1 < n) { cnt[node1] = c1; rowptr[node1] = estart + ex + c0; }
    __syncthreads();
    lcnt[2 * t] = ex;                      // reuse as local fill offsets
    lcnt[2 * t + 1] = ex + c0;
    __syncthreads();
    for (int e = estart + t; e < eend; e += 256) {
        unsigned int p = bedge[e];
        int pos = estart + atomicAdd(&lcnt[p & BMASK], 1);
        col[pos] = (int)(p >> BSHIFT);
    }
}

// ---------------- Layer 1: node transform -> bf16 h1, att coefs ----------------
__global__ __launch_bounds__(256) void k_node1(const float* __restrict__ x,
                                               const float* __restrict__ W1,
                                               const float* __restrict__ att_s,
                                               const float* __restrict__ att_d,
                                               __hip_bfloat162* __restrict__ h1b,
                                               float* __restrict__ as1,
                                               float* __restrict__ ad1, int n) {
    int local = threadIdx.x >> 6;
    int node = blockIdx.x * 4 + local;
    int lane = threadIdx.x & 63;
    __shared__ float xs[4][IN_DIM];
    if (node < n && lane < IN_DIM) xs[local][lane] = x[(size_t)node * IN_DIM + lane];
    __syncthreads();
    if (node >= n) return;
    const float2* W1v = (const float2*)W1;   // [32][64] float2
    float acc0 = 0.f, acc1 = 0.f;
#pragma unroll
    for (int k = 0; k < IN_DIM; k++) {
        float xv = xs[local][k];
        float2 w = W1v[k * 64 + lane];
        acc0 = fmaf(xv, w.x, acc0);
        acc1 = fmaf(xv, w.y, acc1);
    }
    __hip_bfloat162 hv;
    hv.x = __float2bfloat16(acc0);
    hv.y = __float2bfloat16(acc1);
    h1b[(size_t)node * 64 + lane] = hv;
    float2 asv = ((const float2*)att_s)[lane];
    float2 adv = ((const float2*)att_d)[lane];
    float ps = acc0 * asv.x + acc1 * asv.y;
    float pd = acc0 * adv.x + acc1 * adv.y;
#pragma unroll
    for (int off = 16; off; off >>= 1) {       // reduce within 32-lane half = one head
        ps += __shfl_down(ps, off, 32);
        pd += __shfl_down(pd, off, 32);
    }
    if ((lane & 31) == 0) {
        int head = lane >> 5;
        as1[node * 2 + head] = ps;
        ad1[node * 2 + head] = pd;
    }
}

// ---------------- Layer 1 aggregation + bias + LayerNorm + ReLU ----------------
__global__ __launch_bounds__(256) void k_agg1(const __hip_bfloat162* __restrict__ h1b,
                                              const float* __restrict__ as1,
                                              const float* __restrict__ ad1,
                                              const int* __restrict__ rowptr,
                                              const int* __restrict__ cnt,
                                              const int* __restrict__ col,
                                              const float* __restrict__ bias1,
                                              const float* __restrict__ gamma,
                                              const float* __restrict__ beta,
                                              float2* __restrict__ hln, int n) {
    int node = blockIdx.x * 4 + (threadIdx.x >> 6);
    int lane = threadIdx.x & 63;
    if (node >= n) return;
    int head = lane >> 5;
    float ad = ad1[node * 2 + head];
    float w = __expf(leaky(as1[node * 2 + head] + ad));
    __hip_bfloat162 hv = h1b[(size_t)node * 64 + lane];
    float acc0 = w * bf2f(hv.x), acc1 = w * bf2f(hv.y), wsum = w;
    int start = rowptr[node], deg = cnt[node];
    for (int base = 0; base < deg; base += 64) {
        int m = min(64, deg - base);
        int colv = (lane < m) ? col[start + base + lane] : 0;
        int j = 0;
        for (; j + 4 <= m; j += 4) {
            int s0 = __shfl(colv, j + 0);
            int s1 = __shfl(colv, j + 1);
            int s2 = __shfl(colv, j + 2);
            int s3 = __shfl(colv, j + 3);
            float e0 = as1[s0 * 2 + head];
            float e1 = as1[s1 * 2 + head];
            float e2 = as1[s2 * 2 + head];
            float e3 = as1[s3 * 2 + head];
            __hip_bfloat162 g0 = h1b[(size_t)s0 * 64 + lane];
            __hip_bfloat162 g1 = h1b[(size_t)s1 * 64 + lane];
            __hip_bfloat162 g2 = h1b[(size_t)s2 * 64 + lane];
            __hip_bfloat162 g3 = h1b[(size_t)s3 * 64 + lane];
            float w0 = __expf(leaky(e0 + ad));
            float w1 = __expf(leaky(e1 + ad));
            float w2 = __expf(leaky(e2 + ad));
            float w3 = __expf(leaky(e3 + ad));
            acc0 = fmaf(w0, bf2f(g0.x), acc0); acc1 = fmaf(w0, bf2f(g0.y), acc1);
            acc0 = fmaf(w1, bf2f(g1.x), acc0); acc1 = fmaf(w1, bf2f(g1.y), acc1);
            acc0 = fmaf(w2, bf2f(g2.x), acc0); acc1 = fmaf(w2, bf2f(g2.y), acc1);
            acc0 = fmaf(w3, bf2f(g3.x), acc0); acc1 = fmaf(w3, bf2f(g3.y), acc1);
            wsum += w0 + w1 + w2 + w3;
        }
        for (; j < m; j++) {
            int s = __shfl(colv, j);
            float ww = __expf(leaky(as1[s * 2 + head] + ad));
            __hip_bfloat162 g = h1b[(size_t)s * 64 + lane];
            acc0 = fmaf(ww, bf2f(g.x), acc0);
            acc1 = fmaf(ww, bf2f(g.y), acc1);
            wsum += ww;
        }
    }
    float2 bv = ((const float2*)bias1)[lane];
    float o0 = acc0 / (wsum + 1e-16f) + bv.x;
    float o1 = acc1 / (wsum + 1e-16f) + bv.y;
    float sum = o0 + o1, sq = o0 * o0 + o1 * o1;
#pragma unroll
    for (int off = 32; off; off >>= 1) {
        sum += __shfl_xor(sum, off, 64);
        sq += __shfl_xor(sq, off, 64);
    }
    float mu = sum * (1.f / 128.f);
    float var = sq * (1.f / 128.f) - mu * mu;
    float r = rsqrtf(var + LN_EPS);
    float2 gv = ((const float2*)gamma)[lane];
    float2 btv = ((const float2*)beta)[lane];
    float v0 = (o0 - mu) * r * gv.x + btv.x;
    float v1 = (o1 - mu) * r * gv.y + btv.y;
    float2 ov; ov.x = fmaxf(v0, 0.f); ov.y = fmaxf(v1, 0.f);
    hln[(size_t)node * 64 + lane] = ov;
}

// ---------------- Layer 2: node transform -> bf16 h2, att coefs ----------------
__global__ __launch_bounds__(256) void k_node2(const float2* __restrict__ hln,
                                               const float* __restrict__ W2,
                                               const float* __restrict__ att_s2,
                                               const float* __restrict__ att_d2,
                                               __hip_bfloat16* __restrict__ h2b,
                                               float* __restrict__ as2,
                                               float* __restrict__ ad2, int n) {
    int local = threadIdx.x >> 6;
    int node = blockIdx.x * 4 + local;
    int lane = threadIdx.x & 63;
    __shared__ float xs[4][F1];
    if (node < n) {
        ((float2*)xs[local])[lane] = hln[(size_t)node * 64 + lane];
    }
    __syncthreads();
    if (node >= n) return;
    float acc = 0.f;
#pragma unroll 8
    for (int k = 0; k < F1; k++) acc = fmaf(xs[local][k], W2[k * OUT_CH + lane], acc);
    h2b[(size_t)node * OUT_CH + lane] = __float2bfloat16(acc);
    float ps = acc * att_s2[lane];
    float pd = acc * att_d2[lane];
#pragma unroll
    for (int off = 32; off; off >>= 1) {
        ps += __shfl_down(ps, off, 64);
        pd += __shfl_down(pd, off, 64);
    }
    if (lane == 0) { as2[node] = ps; ad2[node] = pd; }
}

// ---------------- Layer 2 aggregation + bias -> output ----------------
__global__ __launch_bounds__(256) void k_agg2(const __hip_bfloat16* __restrict__ h2b,
                                              const float* __restrict__ as2,
                                              const float* __restrict__ ad2,
                                              const int* __restrict__ rowptr,
                                              const int* __restrict__ cnt,
                                              const int* __restrict__ col,
                                              const float* __restrict__ bias2,
                                              float* __restrict__ out, int n) {
    int node = blockIdx.x * 4 + (threadIdx.x >> 6);
    int lane = threadIdx.x & 63;
    if (node >= n) return;
    float adv = ad2[node];
    float w = __expf(leaky(as2[node] + adv));
    float acc = w * bf2f(h2b[(size_t)node * OUT_CH + lane]);
    float wsum = w;
    int start = rowptr[node], deg = cnt[node];
    for (int base = 0; base < deg; base += 64) {
        int m = min(64, deg - base);
        int colv = (lane < m) ? col[start + base + lane] : 0;
        int j = 0;
        for (; j + 4 <= m; j += 4) {
            int s0 = __shfl(colv, j + 0);
            int s1 = __shfl(colv, j + 1);
            int s2 = __shfl(colv, j + 2);
            int s3 = __shfl(colv, j + 3);
            float e0 = as2[s0], e1 = as2[s1], e2 = as2[s2], e3 = as2[s3];
            __hip_bfloat16 g0 = h2b[(size_t)s0 * OUT_CH + lane];
            __hip_bfloat16 g1 = h2b[(size_t)s1 * OUT_CH + lane];
            __hip_bfloat16 g2 = h2b[(size_t)s2 * OUT_CH + lane];
            __hip_bfloat16 g3 = h2b[(size_t)s3 * OUT_CH + lane];
            float w0 = __expf(leaky(e0 + adv));
            float w1 = __expf(leaky(e1 + adv));
            float w2 = __expf(leaky(e2 + adv));
            float w3 = __expf(leaky(e3 + adv));
            acc = fmaf(w0, bf2f(g0), acc);
            acc = fmaf(w1, bf2f(g1), acc);
            acc = fmaf(w2, bf2f(g2), acc);
            acc = fmaf(w3, bf2f(g3), acc);
            wsum += w0 + w1 + w2 + w3;
        }
        for (; j < m; j++) {
            int s = __shfl(colv, j);
            float ww = __expf(leaky(as2[s] + adv));
            acc = fmaf(ww, bf2f(h2b[(size_t)s * OUT_CH + lane]), acc);
            wsum += ww;
        }
    }
    out[(size_t)node * OUT_CH + lane] = acc / (wsum + 1e-16f) + bias2[lane];
}

extern "C" void kernel_launch(void* const* d_in, const int* in_sizes, int n_in,
                              void* d_out, int out_size, void* d_ws, size_t ws_size,
                              hipStream_t stream) {
    const float* x        = (const float*)d_in[0];
    const int*   eidx     = (const int*)d_in[1];
    const float* W1       = (const float*)d_in[2];
    const float* att_src1 = (const float*)d_in[3];
    const float* att_dst1 = (const float*)d_in[4];
    const float* bias1    = (const float*)d_in[5];
    const float* gamma    = (const float*)d_in[6];
    const float* beta     = (const float*)d_in[7];
    const float* W2       = (const float*)d_in[8];
    const float* att_src2 = (const float*)d_in[9];
    const float* att_dst2 = (const float*)d_in[10];
    const float* bias2    = (const float*)d_in[11];
    float* out = (float*)d_out;

    const int N = in_sizes[0] / IN_DIM;      // 100000
    const int E = in_sizes[1] / 2;           // 1600000
    const int* src = eidx;
    const int* dst = eidx + E;
    const int nb = (N + BMASK) >> BSHIFT;    // 196 buckets

    char* w = (char*)d_ws;
    __hip_bfloat162* h1b = (__hip_bfloat162*)w; w += (size_t)N * 64 * 4;   // 25.6 MB
    float2* hln = (float2*)w;                   w += (size_t)N * 64 * 8;   // 51.2 MB
    __hip_bfloat16* h2b = (__hip_bfloat16*)w;   w += (size_t)N * 64 * 2;   // 12.8 MB
    float* as1 = (float*)w; w += (size_t)N * 2 * 4;
    float* ad1 = (float*)w; w += (size_t)N * 2 * 4;
    float* as2 = (float*)w; w += (size_t)N * 4;
    float* ad2 = (float*)w; w += (size_t)N * 4;
    int* cnt    = (int*)w; w += (size_t)N * 4;
    int* rowptr = (int*)w; w += (size_t)N * 4;
    int* bcnt   = (int*)w; w += 512 * 4;
    int* boff   = (int*)w; w += 520 * 4;
    int* bfill  = (int*)w; w += 512 * 4;
    int* col    = (int*)w; w += (size_t)E * 4;
    unsigned int* bedge = (unsigned int*)w; w += (size_t)E * 4;

    const int nchunk = (E + CHUNK - 1) / CHUNK;   // 391

    // ---- bucketed CSR build (shared by both layers) ----
    hipMemsetAsync(bcnt, 0, 512 * 4, stream);
    k_bhist<<<nchunk, 256, 0, stream>>>(dst, E, nb, bcnt);
    k_bscan<<<1, 512, 0, stream>>>(bcnt, nb, E, boff, bfill);
    k_bucket<<<nchunk, 256, 0, stream>>>(src, dst, E, nb, bfill, bedge);
    k_csr<<<nb, 256, 0, stream>>>(bedge, boff, N, cnt, rowptr, col);

    // ---- Layer 1 ----
    k_node1<<<(N + 3) / 4, 256, 0, stream>>>(x, W1, att_src1, att_dst1, h1b, as1, ad1, N);
    k_agg1<<<(N + 3) / 4, 256, 0, stream>>>(h1b, as1, ad1, rowptr, cnt, col,
                                            bias1, gamma, beta, hln, N);
    // ---- Layer 2 ----
    k_node2<<<(N + 3) / 4, 256, 0, stream>>>(hln, W2, att_src2, att_dst2, h2b, as2, ad2, N);
    k_agg2<<<(N + 3) / 4, 256, 0, stream>>>(h2b, as2, ad2, rowptr, cnt, col,
                                            bias2, out, N);
}

// Round 5
// 407.736 us; speedup vs baseline: 2.2722x; 1.1949x over previous
//
#include <hip/hip_runtime.h>
#include <hip/hip_bf16.h>

#define IN_DIM 32
#define HID 64
#define H1 2
#define F1 (H1 * HID)   // 128
#define OUT_CH 64
#define NEG_SLOPE 0.2f
#define LN_EPS 1e-5f

#define BSHIFT 9                     // 512 nodes per bucket
#define BMASK ((1 << BSHIFT) - 1)
#define CHUNK 4096                   // edges per block in bucketing passes

typedef __attribute__((ext_vector_type(8))) short short8x;   // 8 bf16 = 4 VGPRs
typedef __attribute__((ext_vector_type(4))) float floatx4;   // MFMA accumulator

__device__ __forceinline__ float leaky(float x) {
    return x > 0.f ? x : NEG_SLOPE * x;
}
__device__ __forceinline__ float bf2f(__hip_bfloat16 v) { return __bfloat162float(v); }

// ---------------- bucketed CSR build ----------------

__global__ __launch_bounds__(256) void k_bhist(const int* __restrict__ dst, int E, int nb,
                                               int* __restrict__ bcnt) {
    __shared__ int h[512];
    int t = threadIdx.x;
    for (int i = t; i < nb; i += 256) h[i] = 0;
    __syncthreads();
    int base = blockIdx.x * CHUNK;
#pragma unroll
    for (int j = 0; j < 16; j++) {
        int e = base + j * 256 + t;
        if (e < E) atomicAdd(&h[dst[e] >> BSHIFT], 1);
    }
    __syncthreads();
    for (int i = t; i < nb; i += 256)
        if (h[i]) atomicAdd(&bcnt[i], h[i]);
}

__global__ __launch_bounds__(512) void k_bscan(const int* __restrict__ bcnt, int nb, int E,
                                               int* __restrict__ boff,
                                               int* __restrict__ bfill) {
    __shared__ int s[512];
    int t = threadIdx.x;
    int v = (t < nb) ? bcnt[t] : 0;
    s[t] = v;
    __syncthreads();
    for (int off = 1; off < 512; off <<= 1) {
        int u = (t >= off) ? s[t - off] : 0;
        __syncthreads();
        s[t] += u;
        __syncthreads();
    }
    if (t < nb) { int ex = s[t] - v; boff[t] = ex; bfill[t] = ex; }
    if (t == 0) boff[nb] = E;
}

__global__ __launch_bounds__(256) void k_bucket(const int* __restrict__ src,
                                                const int* __restrict__ dst, int E, int nb,
                                                int* __restrict__ bfill,
                                                unsigned int* __restrict__ bedge) {
    __shared__ int h[512];
    __shared__ int gb[512];
    int t = threadIdx.x;
    for (int i = t; i < nb; i += 256) h[i] = 0;
    __syncthreads();
    int base = blockIdx.x * CHUNK;
    unsigned int pk[16];
    int rk[16], bk[16];
#pragma unroll
    for (int j = 0; j < 16; j++) {
        int e = base + j * 256 + t;
        if (e < E) {
            int d = dst[e];
            int b = d >> BSHIFT;
            bk[j] = b;
            pk[j] = ((unsigned)src[e] << BSHIFT) | (unsigned)(d & BMASK);
            rk[j] = atomicAdd(&h[b], 1);
        } else bk[j] = -1;
    }
    __syncthreads();
    for (int i = t; i < nb; i += 256)
        gb[i] = h[i] ? atomicAdd(&bfill[i], h[i]) : 0;
    __syncthreads();
#pragma unroll
    for (int j = 0; j < 16; j++)
        if (bk[j] >= 0) bedge[gb[bk[j]] + rk[j]] = pk[j];
}

__global__ __launch_bounds__(256) void k_csr(const unsigned int* __restrict__ bedge,
                                             const int* __restrict__ boff, int n,
                                             int* __restrict__ cnt,
                                             int* __restrict__ rowptr,
                                             int* __restrict__ col) {
    int b = blockIdx.x;
    int t = threadIdx.x;
    __shared__ int lcnt[512];
    __shared__ int lscan[256];
    int nbase = b << BSHIFT;
    lcnt[2 * t] = 0; lcnt[2 * t + 1] = 0;
    __syncthreads();
    int estart = boff[b], eend = boff[b + 1];
    for (int e = estart + t; e < eend; e += 256)
        atomicAdd(&lcnt[bedge[e] & BMASK], 1);
    __syncthreads();
    int c0 = lcnt[2 * t], c1 = lcnt[2 * t + 1];
    int s = c0 + c1;
    lscan[t] = s;
    __syncthreads();
    for (int off = 1; off < 256; off <<= 1) {
        int u = (t >= off) ? lscan[t - off] : 0;
        __syncthreads();
        lscan[t] += u;
        __syncthreads();
    }
    int ex = lscan[t] - s;
    int node0 = nbase + 2 * t, node1 = node0 + 1;
    if (node0 < n) { cnt[node0] = c0; rowptr[node0] = estart + ex; }
    if (node1 < n) { cnt[node1] = c1; rowptr[node1] = estart + ex + c0; }
    __syncthreads();
    lcnt[2 * t] = ex;
    lcnt[2 * t + 1] = ex + c0;
    __syncthreads();
    for (int e = estart + t; e < eend; e += 256) {
        unsigned int p = bedge[e];
        int pos = estart + atomicAdd(&lcnt[p & BMASK], 1);
        col[pos] = (int)(p >> BSHIFT);
    }
}

// ---------------- Layer 1: node transform -> bf16 h1, att coefs ----------------
__global__ __launch_bounds__(256) void k_node1(const float* __restrict__ x,
                                               const float* __restrict__ W1,
                                               const float* __restrict__ att_s,
                                               const float* __restrict__ att_d,
                                               __hip_bfloat162* __restrict__ h1b,
                                               float* __restrict__ as1,
                                               float* __restrict__ ad1, int n) {
    int local = threadIdx.x >> 6;
    int node = blockIdx.x * 4 + local;
    int lane = threadIdx.x & 63;
    __shared__ float xs[4][IN_DIM];
    if (node < n && lane < IN_DIM) xs[local][lane] = x[(size_t)node * IN_DIM + lane];
    __syncthreads();
    if (node >= n) return;
    const float2* W1v = (const float2*)W1;   // [32][64] float2
    float acc0 = 0.f, acc1 = 0.f;
#pragma unroll
    for (int k = 0; k < IN_DIM; k++) {
        float xv = xs[local][k];
        float2 w = W1v[k * 64 + lane];
        acc0 = fmaf(xv, w.x, acc0);
        acc1 = fmaf(xv, w.y, acc1);
    }
    __hip_bfloat162 hv;
    hv.x = __float2bfloat16(acc0);
    hv.y = __float2bfloat16(acc1);
    h1b[(size_t)node * 64 + lane] = hv;
    float2 asv = ((const float2*)att_s)[lane];
    float2 adv = ((const float2*)att_d)[lane];
    float ps = acc0 * asv.x + acc1 * asv.y;
    float pd = acc0 * adv.x + acc1 * adv.y;
#pragma unroll
    for (int off = 16; off; off >>= 1) {
        ps += __shfl_down(ps, off, 32);
        pd += __shfl_down(pd, off, 32);
    }
    if ((lane & 31) == 0) {
        int head = lane >> 5;
        as1[node * 2 + head] = ps;
        ad1[node * 2 + head] = pd;
    }
}

// ---------------- Layer 1 aggregation + bias + LayerNorm + ReLU -> bf16 hln ----------------
__global__ __launch_bounds__(256) void k_agg1(const __hip_bfloat162* __restrict__ h1b,
                                              const float* __restrict__ as1,
                                              const float* __restrict__ ad1,
                                              const int* __restrict__ rowptr,
                                              const int* __restrict__ cnt,
                                              const int* __restrict__ col,
                                              const float* __restrict__ bias1,
                                              const float* __restrict__ gamma,
                                              const float* __restrict__ beta,
                                              __hip_bfloat162* __restrict__ hlnb, int n) {
    int node = blockIdx.x * 4 + (threadIdx.x >> 6);
    int lane = threadIdx.x & 63;
    if (node >= n) return;
    int head = lane >> 5;
    float ad = ad1[node * 2 + head];
    float w = __expf(leaky(as1[node * 2 + head] + ad));
    __hip_bfloat162 hv = h1b[(size_t)node * 64 + lane];
    float acc0 = w * bf2f(hv.x), acc1 = w * bf2f(hv.y), wsum = w;
    int start = rowptr[node], deg = cnt[node];
    for (int base = 0; base < deg; base += 64) {
        int m = min(64, deg - base);
        int colv = (lane < m) ? col[start + base + lane] : 0;
        int j = 0;
        for (; j + 4 <= m; j += 4) {
            int s0 = __shfl(colv, j + 0);
            int s1 = __shfl(colv, j + 1);
            int s2 = __shfl(colv, j + 2);
            int s3 = __shfl(colv, j + 3);
            float e0 = as1[s0 * 2 + head];
            float e1 = as1[s1 * 2 + head];
            float e2 = as1[s2 * 2 + head];
            float e3 = as1[s3 * 2 + head];
            __hip_bfloat162 g0 = h1b[(size_t)s0 * 64 + lane];
            __hip_bfloat162 g1 = h1b[(size_t)s1 * 64 + lane];
            __hip_bfloat162 g2 = h1b[(size_t)s2 * 64 + lane];
            __hip_bfloat162 g3 = h1b[(size_t)s3 * 64 + lane];
            float w0 = __expf(leaky(e0 + ad));
            float w1 = __expf(leaky(e1 + ad));
            float w2 = __expf(leaky(e2 + ad));
            float w3 = __expf(leaky(e3 + ad));
            acc0 = fmaf(w0, bf2f(g0.x), acc0); acc1 = fmaf(w0, bf2f(g0.y), acc1);
            acc0 = fmaf(w1, bf2f(g1.x), acc0); acc1 = fmaf(w1, bf2f(g1.y), acc1);
            acc0 = fmaf(w2, bf2f(g2.x), acc0); acc1 = fmaf(w2, bf2f(g2.y), acc1);
            acc0 = fmaf(w3, bf2f(g3.x), acc0); acc1 = fmaf(w3, bf2f(g3.y), acc1);
            wsum += w0 + w1 + w2 + w3;
        }
        for (; j < m; j++) {
            int s = __shfl(colv, j);
            float ww = __expf(leaky(as1[s * 2 + head] + ad));
            __hip_bfloat162 g = h1b[(size_t)s * 64 + lane];
            acc0 = fmaf(ww, bf2f(g.x), acc0);
            acc1 = fmaf(ww, bf2f(g.y), acc1);
            wsum += ww;
        }
    }
    float2 bv = ((const float2*)bias1)[lane];
    float o0 = acc0 / (wsum + 1e-16f) + bv.x;
    float o1 = acc1 / (wsum + 1e-16f) + bv.y;
    float sum = o0 + o1, sq = o0 * o0 + o1 * o1;
#pragma unroll
    for (int off = 32; off; off >>= 1) {
        sum += __shfl_xor(sum, off, 64);
        sq += __shfl_xor(sq, off, 64);
    }
    float mu = sum * (1.f / 128.f);
    float var = sq * (1.f / 128.f) - mu * mu;
    float r = rsqrtf(var + LN_EPS);
    float2 gv = ((const float2*)gamma)[lane];
    float2 btv = ((const float2*)beta)[lane];
    float v0 = (o0 - mu) * r * gv.x + btv.x;
    float v1 = (o1 - mu) * r * gv.y + btv.y;
    __hip_bfloat162 ov;
    ov.x = __float2bfloat16(fmaxf(v0, 0.f));
    ov.y = __float2bfloat16(fmaxf(v1, 0.f));
    hlnb[(size_t)node * 64 + lane] = ov;
}

// ---------------- W2 pack: fp32 [128][64] -> bf16 [64 ch][128 k] ----------------
__global__ __launch_bounds__(256) void k_packW2(const float* __restrict__ W2,
                                                __hip_bfloat16* __restrict__ W2t) {
    int idx = blockIdx.x * 256 + threadIdx.x;
    if (idx < F1 * OUT_CH) {
        int ch = idx >> 7, k = idx & 127;
        W2t[idx] = __float2bfloat16(W2[k * OUT_CH + ch]);
    }
}

// ---------------- Layer 2 node transform via MFMA ----------------
// Block = 4 waves = 64 nodes; wave handles a 16-node M-tile x 64 channels.
// A[m=lane&15][k=quad*8+j] from hlnb rows; B[k=quad*8+j][n=lane&15] from W2t rows.
// C layout: col(channel)=lane&15, row(node)=quad*4+reg  [m89 verified].
__global__ __launch_bounds__(256) void k_node2_mfma(const __hip_bfloat16* __restrict__ hlnb,
                                                    const __hip_bfloat16* __restrict__ W2t,
                                                    const float* __restrict__ att_s2,
                                                    const float* __restrict__ att_d2,
                                                    __hip_bfloat16* __restrict__ h2b,
                                                    float* __restrict__ as2,
                                                    float* __restrict__ ad2, int n) {
    int wave = threadIdx.x >> 6;
    int lane = threadIdx.x & 63;
    int row16 = lane & 15;
    int quad = lane >> 4;
    int node0 = blockIdx.x * 64 + wave * 16;

    // preload all B fragments: 4 K-chunks x 4 N-tiles (64 VGPRs)
    short8x bfr[4][4];
#pragma unroll
    for (int nt = 0; nt < 4; nt++) {
        const __hip_bfloat16* wrow = W2t + (nt * 16 + row16) * F1 + quad * 8;
#pragma unroll
        for (int kc = 0; kc < 4; kc++)
            bfr[kc][nt] = *(const short8x*)(wrow + kc * 32);
    }

    floatx4 acc[4];
#pragma unroll
    for (int nt = 0; nt < 4; nt++) acc[nt] = (floatx4){0.f, 0.f, 0.f, 0.f};

    int arow = node0 + row16;
    if (arow >= n) arow = n - 1;               // clamp; garbage rows never written
    const __hip_bfloat16* aptr = hlnb + (size_t)arow * F1 + quad * 8;
#pragma unroll
    for (int kc = 0; kc < 4; kc++) {
        short8x af = *(const short8x*)(aptr + kc * 32);
#pragma unroll
        for (int nt = 0; nt < 4; nt++)
            acc[nt] = __builtin_amdgcn_mfma_f32_16x16x32_bf16(af, bfr[kc][nt], acc[nt], 0, 0, 0);
    }

    float asv[4], adv[4];
#pragma unroll
    for (int nt = 0; nt < 4; nt++) {
        asv[nt] = att_s2[nt * 16 + row16];
        adv[nt] = att_d2[nt * 16 + row16];
    }
#pragma unroll
    for (int rr = 0; rr < 4; rr++) {
        int node = node0 + quad * 4 + rr;
        float ps = 0.f, pd = 0.f;
#pragma unroll
        for (int nt = 0; nt < 4; nt++) {
            float v = acc[nt][rr];
            if (node < n) h2b[(size_t)node * OUT_CH + nt * 16 + row16] = __float2bfloat16(v);
            ps = fmaf(v, asv[nt], ps);
            pd = fmaf(v, adv[nt], pd);
        }
#pragma unroll
        for (int off = 1; off < 16; off <<= 1) {   // reduce across the 16-lane group
            ps += __shfl_xor(ps, off, 64);
            pd += __shfl_xor(pd, off, 64);
        }
        if (row16 == 0 && node < n) { as2[node] = ps; ad2[node] = pd; }
    }
}

// ---------------- Layer 2 aggregation + bias -> output ----------------
__global__ __launch_bounds__(256) void k_agg2(const __hip_bfloat16* __restrict__ h2b,
                                              const float* __restrict__ as2,
                                              const float* __restrict__ ad2,
                                              const int* __restrict__ rowptr,
                                              const int* __restrict__ cnt,
                                              const int* __restrict__ col,
                                              const float* __restrict__ bias2,
                                              float* __restrict__ out, int n) {
    int node = blockIdx.x * 4 + (threadIdx.x >> 6);
    int lane = threadIdx.x & 63;
    if (node >= n) return;
    float adv = ad2[node];
    float w = __expf(leaky(as2[node] + adv));
    float acc = w * bf2f(h2b[(size_t)node * OUT_CH + lane]);
    float wsum = w;
    int start = rowptr[node], deg = cnt[node];
    for (int base = 0; base < deg; base += 64) {
        int m = min(64, deg - base);
        int colv = (lane < m) ? col[start + base + lane] : 0;
        int j = 0;
        for (; j + 4 <= m; j += 4) {
            int s0 = __shfl(colv, j + 0);
            int s1 = __shfl(colv, j + 1);
            int s2 = __shfl(colv, j + 2);
            int s3 = __shfl(colv, j + 3);
            float e0 = as2[s0], e1 = as2[s1], e2 = as2[s2], e3 = as2[s3];
            __hip_bfloat16 g0 = h2b[(size_t)s0 * OUT_CH + lane];
            __hip_bfloat16 g1 = h2b[(size_t)s1 * OUT_CH + lane];
            __hip_bfloat16 g2 = h2b[(size_t)s2 * OUT_CH + lane];
            __hip_bfloat16 g3 = h2b[(size_t)s3 * OUT_CH + lane];
            float w0 = __expf(leaky(e0 + adv));
            float w1 = __expf(leaky(e1 + adv));
            float w2 = __expf(leaky(e2 + adv));
            float w3 = __expf(leaky(e3 + adv));
            acc = fmaf(w0, bf2f(g0), acc);
            acc = fmaf(w1, bf2f(g1), acc);
            acc = fmaf(w2, bf2f(g2), acc);
            acc = fmaf(w3, bf2f(g3), acc);
            wsum += w0 + w1 + w2 + w3;
        }
        for (; j < m; j++) {
            int s = __shfl(colv, j);
            float ww = __expf(leaky(as2[s] + adv));
            acc = fmaf(ww, bf2f(h2b[(size_t)s * OUT_CH + lane]), acc);
            wsum += ww;
        }
    }
    out[(size_t)node * OUT_CH + lane] = acc / (wsum + 1e-16f) + bias2[lane];
}

extern "C" void kernel_launch(void* const* d_in, const int* in_sizes, int n_in,
                              void* d_out, int out_size, void* d_ws, size_t ws_size,
                              hipStream_t stream) {
    const float* x        = (const float*)d_in[0];
    const int*   eidx     = (const int*)d_in[1];
    const float* W1       = (const float*)d_in[2];
    const float* att_src1 = (const float*)d_in[3];
    const float* att_dst1 = (const float*)d_in[4];
    const float* bias1    = (const float*)d_in[5];
    const float* gamma    = (const float*)d_in[6];
    const float* beta     = (const float*)d_in[7];
    const float* W2       = (const float*)d_in[8];
    const float* att_src2 = (const float*)d_in[9];
    const float* att_dst2 = (const float*)d_in[10];
    const float* bias2    = (const float*)d_in[11];
    float* out = (float*)d_out;

    const int N = in_sizes[0] / IN_DIM;      // 100000
    const int E = in_sizes[1] / 2;           // 1600000
    const int* src = eidx;
    const int* dst = eidx + E;
    const int nb = (N + BMASK) >> BSHIFT;    // 196 buckets

    char* w = (char*)d_ws;
    __hip_bfloat162* h1b  = (__hip_bfloat162*)w; w += (size_t)N * 64 * 4;   // 25.6 MB
    __hip_bfloat162* hlnb = (__hip_bfloat162*)w; w += (size_t)N * 64 * 4;   // 25.6 MB
    __hip_bfloat16* h2b   = (__hip_bfloat16*)w;  w += (size_t)N * 64 * 2;   // 12.8 MB
    __hip_bfloat16* W2t   = (__hip_bfloat16*)w;  w += F1 * OUT_CH * 2;
    float* as1 = (float*)w; w += (size_t)N * 2 * 4;
    float* ad1 = (float*)w; w += (size_t)N * 2 * 4;
    float* as2 = (float*)w; w += (size_t)N * 4;
    float* ad2 = (float*)w; w += (size_t)N * 4;
    int* cnt    = (int*)w; w += (size_t)N * 4;
    int* rowptr = (int*)w; w += (size_t)N * 4;
    int* bcnt   = (int*)w; w += 512 * 4;
    int* boff   = (int*)w; w += 520 * 4;
    int* bfill  = (int*)w; w += 512 * 4;
    int* col    = (int*)w; w += (size_t)E * 4;
    unsigned int* bedge = (unsigned int*)w; w += (size_t)E * 4;

    const int nchunk = (E + CHUNK - 1) / CHUNK;   // 391

    // ---- bucketed CSR build (shared by both layers) ----
    hipMemsetAsync(bcnt, 0, 512 * 4, stream);
    k_bhist<<<nchunk, 256, 0, stream>>>(dst, E, nb, bcnt);
    k_bscan<<<1, 512, 0, stream>>>(bcnt, nb, E, boff, bfill);
    k_bucket<<<nchunk, 256, 0, stream>>>(src, dst, E, nb, bfill, bedge);
    k_csr<<<nb, 256, 0, stream>>>(bedge, boff, N, cnt, rowptr, col);

    // ---- Layer 1 ----
    k_node1<<<(N + 3) / 4, 256, 0, stream>>>(x, W1, att_src1, att_dst1, h1b, as1, ad1, N);
    k_agg1<<<(N + 3) / 4, 256, 0, stream>>>(h1b, as1, ad1, rowptr, cnt, col,
                                            bias1, gamma, beta, hlnb, N);
    // ---- Layer 2 ----
    k_packW2<<<(F1 * OUT_CH + 255) / 256, 256, 0, stream>>>(W2, W2t);
    k_node2_mfma<<<(N + 63) / 64, 256, 0, stream>>>((const __hip_bfloat16*)hlnb, W2t,
                                                    att_src2, att_dst2, h2b, as2, ad2, N);
    k_agg2<<<(N + 3) / 4, 256, 0, stream>>>(h2b, as2, ad2, rowptr, cnt, col,
                                            bias2, out, N);
}

// Round 6
// 323.009 us; speedup vs baseline: 2.8682x; 1.2623x over previous
//
#include <hip/hip_runtime.h>
#include <hip/hip_bf16.h>

#define IN_DIM 32
#define HID 64
#define H1 2
#define F1 (H1 * HID)   // 128
#define OUT_CH 64
#define NEG_SLOPE 0.2f
#define LN_EPS 1e-5f

#define BSHIFT 9                     // 512 nodes per bucket
#define BMASK ((1 << BSHIFT) - 1)
#define CHUNK 4096                   // edges per block in bucketing passes

typedef __attribute__((ext_vector_type(8))) short short8x;   // 8 bf16 = 4 VGPRs
typedef __attribute__((ext_vector_type(4))) float floatx4;   // MFMA accumulator

__device__ __forceinline__ float leaky(float x) {
    return x > 0.f ? x : NEG_SLOPE * x;
}
__device__ __forceinline__ float bf2f(__hip_bfloat16 v) { return __bfloat162float(v); }
__device__ __forceinline__ short f2bs(float v) {
    __hip_bfloat16 t = __float2bfloat16(v);
    return *reinterpret_cast<short*>(&t);
}

// ---------------- bucketed CSR build ----------------

__global__ __launch_bounds__(256) void k_bhist(const int* __restrict__ dst, int E, int nb,
                                               int* __restrict__ bcnt) {
    __shared__ int h[512];
    int t = threadIdx.x;
    for (int i = t; i < nb; i += 256) h[i] = 0;
    __syncthreads();
    int base = blockIdx.x * CHUNK;
#pragma unroll
    for (int j = 0; j < 16; j++) {
        int e = base + j * 256 + t;
        if (e < E) atomicAdd(&h[dst[e] >> BSHIFT], 1);
    }
    __syncthreads();
    for (int i = t; i < nb; i += 256)
        if (h[i]) atomicAdd(&bcnt[i], h[i]);
}

__global__ __launch_bounds__(512) void k_bscan(const int* __restrict__ bcnt, int nb, int E,
                                               int* __restrict__ boff,
                                               int* __restrict__ bfill) {
    __shared__ int s[512];
    int t = threadIdx.x;
    int v = (t < nb) ? bcnt[t] : 0;
    s[t] = v;
    __syncthreads();
    for (int off = 1; off < 512; off <<= 1) {
        int u = (t >= off) ? s[t - off] : 0;
        __syncthreads();
        s[t] += u;
        __syncthreads();
    }
    if (t < nb) { int ex = s[t] - v; boff[t] = ex; bfill[t] = ex; }
    if (t == 0) boff[nb] = E;
}

__global__ __launch_bounds__(256) void k_bucket(const int* __restrict__ src,
                                                const int* __restrict__ dst, int E, int nb,
                                                int* __restrict__ bfill,
                                                unsigned int* __restrict__ bedge) {
    __shared__ int h[512];
    __shared__ int gb[512];
    int t = threadIdx.x;
    for (int i = t; i < nb; i += 256) h[i] = 0;
    __syncthreads();
    int base = blockIdx.x * CHUNK;
    unsigned int pk[16];
    int rk[16], bk[16];
#pragma unroll
    for (int j = 0; j < 16; j++) {
        int e = base + j * 256 + t;
        if (e < E) {
            int d = dst[e];
            int b = d >> BSHIFT;
            bk[j] = b;
            pk[j] = ((unsigned)src[e] << BSHIFT) | (unsigned)(d & BMASK);
            rk[j] = atomicAdd(&h[b], 1);
        } else bk[j] = -1;
    }
    __syncthreads();
    for (int i = t; i < nb; i += 256)
        gb[i] = h[i] ? atomicAdd(&bfill[i], h[i]) : 0;
    __syncthreads();
#pragma unroll
    for (int j = 0; j < 16; j++)
        if (bk[j] >= 0) bedge[gb[bk[j]] + rk[j]] = pk[j];
}

__global__ __launch_bounds__(256) void k_csr(const unsigned int* __restrict__ bedge,
                                             const int* __restrict__ boff, int n,
                                             int* __restrict__ cnt,
                                             int* __restrict__ rowptr,
                                             int* __restrict__ col) {
    int b = blockIdx.x;
    int t = threadIdx.x;
    __shared__ int lcnt[512];
    __shared__ int lscan[256];
    int nbase = b << BSHIFT;
    lcnt[2 * t] = 0; lcnt[2 * t + 1] = 0;
    __syncthreads();
    int estart = boff[b], eend = boff[b + 1];
    for (int e = estart + t; e < eend; e += 256)
        atomicAdd(&lcnt[bedge[e] & BMASK], 1);
    __syncthreads();
    int c0 = lcnt[2 * t], c1 = lcnt[2 * t + 1];
    int s = c0 + c1;
    lscan[t] = s;
    __syncthreads();
    for (int off = 1; off < 256; off <<= 1) {
        int u = (t >= off) ? lscan[t - off] : 0;
        __syncthreads();
        lscan[t] += u;
        __syncthreads();
    }
    int ex = lscan[t] - s;
    int node0 = nbase + 2 * t, node1 = node0 + 1;
    if (node0 < n) { cnt[node0] = c0; rowptr[node0] = estart + ex; }
    if (node1 < n) { cnt[node1] = c1; rowptr[node1] = estart + ex + c0; }
    __syncthreads();
    lcnt[2 * t] = ex;
    lcnt[2 * t + 1] = ex + c0;
    __syncthreads();
    for (int e = estart + t; e < eend; e += 256) {
        unsigned int p = bedge[e];
        int pos = estart + atomicAdd(&lcnt[p & BMASK], 1);
        col[pos] = (int)(p >> BSHIFT);
    }
}

// ---------------- W1 pack: fp32 [32][128] -> bf16 [128 ch][32 k] ----------------
__global__ __launch_bounds__(256) void k_packW1(const float* __restrict__ W1,
                                                __hip_bfloat16* __restrict__ W1t) {
    int idx = blockIdx.x * 256 + threadIdx.x;
    if (idx < IN_DIM * F1) {
        int ch = idx >> 5, k = idx & 31;
        W1t[idx] = __float2bfloat16(W1[k * F1 + ch]);
    }
}

// ---------------- Layer 1 node transform via MFMA ----------------
// Block = 4 waves = 64 nodes; wave = 16-node M-tile x 128 channels.
// K=32 = one MFMA K-step. A from x (fp32->bf16 in-register), B from W1t.
// C layout: col(ch)=lane&15 within N-tile, row(node)=quad*4+reg [m89].
__global__ __launch_bounds__(256) void k_node1_mfma(const float* __restrict__ x,
                                                    const __hip_bfloat16* __restrict__ W1t,
                                                    const float* __restrict__ att_s,
                                                    const float* __restrict__ att_d,
                                                    __hip_bfloat16* __restrict__ h1b,
                                                    float* __restrict__ as1,
                                                    float* __restrict__ ad1, int n) {
    int wave = threadIdx.x >> 6;
    int lane = threadIdx.x & 63;
    int row16 = lane & 15;
    int quad = lane >> 4;
    int node0 = blockIdx.x * 64 + wave * 16;

    // B fragments: 8 N-tiles of 16 channels, one 16B load each
    short8x bfr[8];
#pragma unroll
    for (int nt = 0; nt < 8; nt++)
        bfr[nt] = *(const short8x*)(W1t + (nt * 16 + row16) * IN_DIM + quad * 8);

    // A fragment: x row, fp32 -> bf16
    int arow = node0 + row16;
    if (arow >= n) arow = n - 1;
    const float* xp = x + (size_t)arow * IN_DIM + quad * 8;
    float4 xa = *(const float4*)xp;
    float4 xb = *(const float4*)(xp + 4);
    short8x af;
    af[0] = f2bs(xa.x); af[1] = f2bs(xa.y); af[2] = f2bs(xa.z); af[3] = f2bs(xa.w);
    af[4] = f2bs(xb.x); af[5] = f2bs(xb.y); af[6] = f2bs(xb.z); af[7] = f2bs(xb.w);

    floatx4 acc[8];
#pragma unroll
    for (int nt = 0; nt < 8; nt++) acc[nt] = (floatx4){0.f, 0.f, 0.f, 0.f};
#pragma unroll
    for (int nt = 0; nt < 8; nt++)
        acc[nt] = __builtin_amdgcn_mfma_f32_16x16x32_bf16(af, bfr[nt], acc[nt], 0, 0, 0);

    float asv[8], adv[8];
#pragma unroll
    for (int nt = 0; nt < 8; nt++) {
        asv[nt] = att_s[nt * 16 + row16];
        adv[nt] = att_d[nt * 16 + row16];
    }
#pragma unroll
    for (int rr = 0; rr < 4; rr++) {
        int node = node0 + quad * 4 + rr;
        float ps0 = 0.f, pd0 = 0.f, ps1 = 0.f, pd1 = 0.f;
#pragma unroll
        for (int nt = 0; nt < 8; nt++) {
            float v = acc[nt][rr];
            if (node < n) h1b[(size_t)node * F1 + nt * 16 + row16] = __float2bfloat16(v);
            if (nt < 4) { ps0 = fmaf(v, asv[nt], ps0); pd0 = fmaf(v, adv[nt], pd0); }
            else        { ps1 = fmaf(v, asv[nt], ps1); pd1 = fmaf(v, adv[nt], pd1); }
        }
#pragma unroll
        for (int off = 1; off < 16; off <<= 1) {
            ps0 += __shfl_xor(ps0, off, 64);
            pd0 += __shfl_xor(pd0, off, 64);
            ps1 += __shfl_xor(ps1, off, 64);
            pd1 += __shfl_xor(pd1, off, 64);
        }
        if (row16 == 0 && node < n) {
            as1[node * 2 + 0] = ps0; ad1[node * 2 + 0] = pd0;
            as1[node * 2 + 1] = ps1; ad1[node * 2 + 1] = pd1;
        }
    }
}

// ---------------- Layer 1 aggregation + bias + LayerNorm + ReLU -> bf16 hln ----------------
__global__ __launch_bounds__(256) void k_agg1(const __hip_bfloat162* __restrict__ h1b,
                                              const float* __restrict__ as1,
                                              const float* __restrict__ ad1,
                                              const int* __restrict__ rowptr,
                                              const int* __restrict__ cnt,
                                              const int* __restrict__ col,
                                              const float* __restrict__ bias1,
                                              const float* __restrict__ gamma,
                                              const float* __restrict__ beta,
                                              __hip_bfloat162* __restrict__ hlnb, int n) {
    int node = blockIdx.x * 4 + (threadIdx.x >> 6);
    int lane = threadIdx.x & 63;
    if (node >= n) return;
    int head = lane >> 5;
    float ad = ad1[node * 2 + head];
    float w = __expf(leaky(as1[node * 2 + head] + ad));
    __hip_bfloat162 hv = h1b[(size_t)node * 64 + lane];
    float acc0 = w * bf2f(hv.x), acc1 = w * bf2f(hv.y), wsum = w;
    int start = rowptr[node], deg = cnt[node];
    for (int base = 0; base < deg; base += 64) {
        int m = min(64, deg - base);
        int colv = (lane < m) ? col[start + base + lane] : 0;
        int j = 0;
        for (; j + 4 <= m; j += 4) {
            int s0 = __shfl(colv, j + 0);
            int s1 = __shfl(colv, j + 1);
            int s2 = __shfl(colv, j + 2);
            int s3 = __shfl(colv, j + 3);
            float e0 = as1[s0 * 2 + head];
            float e1 = as1[s1 * 2 + head];
            float e2 = as1[s2 * 2 + head];
            float e3 = as1[s3 * 2 + head];
            __hip_bfloat162 g0 = h1b[(size_t)s0 * 64 + lane];
            __hip_bfloat162 g1 = h1b[(size_t)s1 * 64 + lane];
            __hip_bfloat162 g2 = h1b[(size_t)s2 * 64 + lane];
            __hip_bfloat162 g3 = h1b[(size_t)s3 * 64 + lane];
            float w0 = __expf(leaky(e0 + ad));
            float w1 = __expf(leaky(e1 + ad));
            float w2 = __expf(leaky(e2 + ad));
            float w3 = __expf(leaky(e3 + ad));
            acc0 = fmaf(w0, bf2f(g0.x), acc0); acc1 = fmaf(w0, bf2f(g0.y), acc1);
            acc0 = fmaf(w1, bf2f(g1.x), acc0); acc1 = fmaf(w1, bf2f(g1.y), acc1);
            acc0 = fmaf(w2, bf2f(g2.x), acc0); acc1 = fmaf(w2, bf2f(g2.y), acc1);
            acc0 = fmaf(w3, bf2f(g3.x), acc0); acc1 = fmaf(w3, bf2f(g3.y), acc1);
            wsum += w0 + w1 + w2 + w3;
        }
        for (; j < m; j++) {
            int s = __shfl(colv, j);
            float ww = __expf(leaky(as1[s * 2 + head] + ad));
            __hip_bfloat162 g = h1b[(size_t)s * 64 + lane];
            acc0 = fmaf(ww, bf2f(g.x), acc0);
            acc1 = fmaf(ww, bf2f(g.y), acc1);
            wsum += ww;
        }
    }
    float2 bv = ((const float2*)bias1)[lane];
    float o0 = acc0 / (wsum + 1e-16f) + bv.x;
    float o1 = acc1 / (wsum + 1e-16f) + bv.y;
    float sum = o0 + o1, sq = o0 * o0 + o1 * o1;
#pragma unroll
    for (int off = 32; off; off >>= 1) {
        sum += __shfl_xor(sum, off, 64);
        sq += __shfl_xor(sq, off, 64);
    }
    float mu = sum * (1.f / 128.f);
    float var = sq * (1.f / 128.f) - mu * mu;
    float r = rsqrtf(var + LN_EPS);
    float2 gv = ((const float2*)gamma)[lane];
    float2 btv = ((const float2*)beta)[lane];
    float v0 = (o0 - mu) * r * gv.x + btv.x;
    float v1 = (o1 - mu) * r * gv.y + btv.y;
    __hip_bfloat162 ov;
    ov.x = __float2bfloat16(fmaxf(v0, 0.f));
    ov.y = __float2bfloat16(fmaxf(v1, 0.f));
    hlnb[(size_t)node * 64 + lane] = ov;
}

// ---------------- W2 pack: fp32 [128][64] -> bf16 [64 ch][128 k] ----------------
__global__ __launch_bounds__(256) void k_packW2(const float* __restrict__ W2,
                                                __hip_bfloat16* __restrict__ W2t) {
    int idx = blockIdx.x * 256 + threadIdx.x;
    if (idx < F1 * OUT_CH) {
        int ch = idx >> 7, k = idx & 127;
        W2t[idx] = __float2bfloat16(W2[k * OUT_CH + ch]);
    }
}

// ---------------- Layer 2 node transform via MFMA ----------------
__global__ __launch_bounds__(256) void k_node2_mfma(const __hip_bfloat16* __restrict__ hlnb,
                                                    const __hip_bfloat16* __restrict__ W2t,
                                                    const float* __restrict__ att_s2,
                                                    const float* __restrict__ att_d2,
                                                    __hip_bfloat16* __restrict__ h2b,
                                                    float* __restrict__ as2,
                                                    float* __restrict__ ad2, int n) {
    int wave = threadIdx.x >> 6;
    int lane = threadIdx.x & 63;
    int row16 = lane & 15;
    int quad = lane >> 4;
    int node0 = blockIdx.x * 64 + wave * 16;

    short8x bfr[4][4];
#pragma unroll
    for (int nt = 0; nt < 4; nt++) {
        const __hip_bfloat16* wrow = W2t + (nt * 16 + row16) * F1 + quad * 8;
#pragma unroll
        for (int kc = 0; kc < 4; kc++)
            bfr[kc][nt] = *(const short8x*)(wrow + kc * 32);
    }

    floatx4 acc[4];
#pragma unroll
    for (int nt = 0; nt < 4; nt++) acc[nt] = (floatx4){0.f, 0.f, 0.f, 0.f};

    int arow = node0 + row16;
    if (arow >= n) arow = n - 1;
    const __hip_bfloat16* aptr = hlnb + (size_t)arow * F1 + quad * 8;
#pragma unroll
    for (int kc = 0; kc < 4; kc++) {
        short8x af = *(const short8x*)(aptr + kc * 32);
#pragma unroll
        for (int nt = 0; nt < 4; nt++)
            acc[nt] = __builtin_amdgcn_mfma_f32_16x16x32_bf16(af, bfr[kc][nt], acc[nt], 0, 0, 0);
    }

    float asv[4], adv[4];
#pragma unroll
    for (int nt = 0; nt < 4; nt++) {
        asv[nt] = att_s2[nt * 16 + row16];
        adv[nt] = att_d2[nt * 16 + row16];
    }
#pragma unroll
    for (int rr = 0; rr < 4; rr++) {
        int node = node0 + quad * 4 + rr;
        float ps = 0.f, pd = 0.f;
#pragma unroll
        for (int nt = 0; nt < 4; nt++) {
            float v = acc[nt][rr];
            if (node < n) h2b[(size_t)node * OUT_CH + nt * 16 + row16] = __float2bfloat16(v);
            ps = fmaf(v, asv[nt], ps);
            pd = fmaf(v, adv[nt], pd);
        }
#pragma unroll
        for (int off = 1; off < 16; off <<= 1) {
            ps += __shfl_xor(ps, off, 64);
            pd += __shfl_xor(pd, off, 64);
        }
        if (row16 == 0 && node < n) { as2[node] = ps; ad2[node] = pd; }
    }
}

// ---------------- Layer 2 aggregation + bias -> output ----------------
__global__ __launch_bounds__(256) void k_agg2(const __hip_bfloat16* __restrict__ h2b,
                                              const float* __restrict__ as2,
                                              const float* __restrict__ ad2,
                                              const int* __restrict__ rowptr,
                                              const int* __restrict__ cnt,
                                              const int* __restrict__ col,
                                              const float* __restrict__ bias2,
                                              float* __restrict__ out, int n) {
    int node = blockIdx.x * 4 + (threadIdx.x >> 6);
    int lane = threadIdx.x & 63;
    if (node >= n) return;
    float adv = ad2[node];
    float w = __expf(leaky(as2[node] + adv));
    float acc = w * bf2f(h2b[(size_t)node * OUT_CH + lane]);
    float wsum = w;
    int start = rowptr[node], deg = cnt[node];
    for (int base = 0; base < deg; base += 64) {
        int m = min(64, deg - base);
        int colv = (lane < m) ? col[start + base + lane] : 0;
        int j = 0;
        for (; j + 4 <= m; j += 4) {
            int s0 = __shfl(colv, j + 0);
            int s1 = __shfl(colv, j + 1);
            int s2 = __shfl(colv, j + 2);
            int s3 = __shfl(colv, j + 3);
            float e0 = as2[s0], e1 = as2[s1], e2 = as2[s2], e3 = as2[s3];
            __hip_bfloat16 g0 = h2b[(size_t)s0 * OUT_CH + lane];
            __hip_bfloat16 g1 = h2b[(size_t)s1 * OUT_CH + lane];
            __hip_bfloat16 g2 = h2b[(size_t)s2 * OUT_CH + lane];
            __hip_bfloat16 g3 = h2b[(size_t)s3 * OUT_CH + lane];
            float w0 = __expf(leaky(e0 + adv));
            float w1 = __expf(leaky(e1 + adv));
            float w2 = __expf(leaky(e2 + adv));
            float w3 = __expf(leaky(e3 + adv));
            acc = fmaf(w0, bf2f(g0), acc);
            acc = fmaf(w1, bf2f(g1), acc);
            acc = fmaf(w2, bf2f(g2), acc);
            acc = fmaf(w3, bf2f(g3), acc);
            wsum += w0 + w1 + w2 + w3;
        }
        for (; j < m; j++) {
            int s = __shfl(colv, j);
            float ww = __expf(leaky(as2[s] + adv));
            acc = fmaf(ww, bf2f(h2b[(size_t)s * OUT_CH + lane]), acc);
            wsum += ww;
        }
    }
    out[(size_t)node * OUT_CH + lane] = acc / (wsum + 1e-16f) + bias2[lane];
}

extern "C" void kernel_launch(void* const* d_in, const int* in_sizes, int n_in,
                              void* d_out, int out_size, void* d_ws, size_t ws_size,
                              hipStream_t stream) {
    const float* x        = (const float*)d_in[0];
    const int*   eidx     = (const int*)d_in[1];
    const float* W1       = (const float*)d_in[2];
    const float* att_src1 = (const float*)d_in[3];
    const float* att_dst1 = (const float*)d_in[4];
    const float* bias1    = (const float*)d_in[5];
    const float* gamma    = (const float*)d_in[6];
    const float* beta     = (const float*)d_in[7];
    const float* W2       = (const float*)d_in[8];
    const float* att_src2 = (const float*)d_in[9];
    const float* att_dst2 = (const float*)d_in[10];
    const float* bias2    = (const float*)d_in[11];
    float* out = (float*)d_out;

    const int N = in_sizes[0] / IN_DIM;      // 100000
    const int E = in_sizes[1] / 2;           // 1600000
    const int* src = eidx;
    const int* dst = eidx + E;
    const int nb = (N + BMASK) >> BSHIFT;    // 196 buckets

    char* w = (char*)d_ws;
    __hip_bfloat162* h1b  = (__hip_bfloat162*)w; w += (size_t)N * 64 * 4;   // 25.6 MB
    __hip_bfloat162* hlnb = (__hip_bfloat162*)w; w += (size_t)N * 64 * 4;   // 25.6 MB
    __hip_bfloat16* h2b   = (__hip_bfloat16*)w;  w += (size_t)N * 64 * 2;   // 12.8 MB
    __hip_bfloat16* W1t   = (__hip_bfloat16*)w;  w += IN_DIM * F1 * 2;
    __hip_bfloat16* W2t   = (__hip_bfloat16*)w;  w += F1 * OUT_CH * 2;
    float* as1 = (float*)w; w += (size_t)N * 2 * 4;
    float* ad1 = (float*)w; w += (size_t)N * 2 * 4;
    float* as2 = (float*)w; w += (size_t)N * 4;
    float* ad2 = (float*)w; w += (size_t)N * 4;
    int* cnt    = (int*)w; w += (size_t)N * 4;
    int* rowptr = (int*)w; w += (size_t)N * 4;
    int* bcnt   = (int*)w; w += 512 * 4;
    int* boff   = (int*)w; w += 520 * 4;
    int* bfill  = (int*)w; w += 512 * 4;
    int* col    = (int*)w; w += (size_t)E * 4;
    unsigned int* bedge = (unsigned int*)w; w += (size_t)E * 4;

    const int nchunk = (E + CHUNK - 1) / CHUNK;   // 391

    // ---- bucketed CSR build (shared by both layers) ----
    hipMemsetAsync(bcnt, 0, 512 * 4, stream);
    k_bhist<<<nchunk, 256, 0, stream>>>(dst, E, nb, bcnt);
    k_bscan<<<1, 512, 0, stream>>>(bcnt, nb, E, boff, bfill);
    k_bucket<<<nchunk, 256, 0, stream>>>(src, dst, E, nb, bfill, bedge);
    k_csr<<<nb, 256, 0, stream>>>(bedge, boff, N, cnt, rowptr, col);

    // ---- Layer 1 ----
    k_packW1<<<(IN_DIM * F1 + 255) / 256, 256, 0, stream>>>(W1, W1t);
    k_node1_mfma<<<(N + 63) / 64, 256, 0, stream>>>(x, W1t, att_src1, att_dst1,
                                                    (__hip_bfloat16*)h1b, as1, ad1, N);
    k_agg1<<<(N + 3) / 4, 256, 0, stream>>>(h1b, as1, ad1, rowptr, cnt, col,
                                            bias1, gamma, beta, hlnb, N);
    // ---- Layer 2 ----
    k_packW2<<<(F1 * OUT_CH + 255) / 256, 256, 0, stream>>>(W2, W2t);
    k_node2_mfma<<<(N + 63) / 64, 256, 0, stream>>>((const __hip_bfloat16*)hlnb, W2t,
                                                    att_src2, att_dst2, h2b, as2, ad2, N);
    k_agg2<<<(N + 3) / 4, 256, 0, stream>>>(h2b, as2, ad2, rowptr, cnt, col,
                                            bias2, out, N);
}